// Round 8
// baseline (1610.316 us; speedup 1.0000x reference)
//
#include <hip/hip_runtime.h>
#include <hip/hip_bf16.h>
#include <math.h>

#define NN 100000
#define NE 1600000
#define NR 8
#define DD 64
#define DDR 64

// ---- order-preserving float<->uint encoding (fallback path only) ----
__device__ __forceinline__ unsigned enc_f(float f) {
    unsigned u = __float_as_uint(f);
    return (u & 0x80000000u) ? ~u : (u | 0x80000000u);
}
__device__ __forceinline__ float dec_f(unsigned u) {
    return (u & 0x80000000u) ? __uint_as_float(u & 0x7FFFFFFFu) : __uint_as_float(~u);
}

__device__ __forceinline__ float bflo(unsigned u) { return __uint_as_float(u << 16); }
__device__ __forceinline__ float bfhi(unsigned u) { return __uint_as_float(u & 0xFFFF0000u); }

// ---- Kernel P3: proj[r][n][k] = emb[n] @ W_R[r] (register-budget-safe) ----
// Each lane holds HALF a W column (32 floats) -> ~45 live VGPRs, under the
// observed 64-VGPR allocator cap (larger arrays spill -> phantom GBs of HBM).
__global__ void __launch_bounds__(256)
k_proj3(const float* __restrict__ emb, const float* __restrict__ WR,
        unsigned short* __restrict__ proj)
{
    int t = threadIdx.x;
    int wv = t >> 6;
    int lane = t & 63;
    int c = lane & 31;
    int h = lane >> 5;
    int q = wv & 1;
    int p = wv >> 1;
    int r = blockIdx.y;
    int col = q * 32 + c;
    const float* __restrict__ Wr = WR + ((long)r * DD + h * 32) * DDR + col;
    float w[32];
#pragma unroll
    for (int d = 0; d < 32; ++d) w[d] = Wr[d * DDR];   // coalesced, once per wave
    int nbase = blockIdx.x * 32 + p * 16;
    int nend = (nbase + 16 < NN) ? (nbase + 16) : NN;
    for (int n = nbase; n < nend; ++n) {
        const float* __restrict__ x = emb + (long)n * DD + h * 32;
        float acc = 0.f;
#pragma unroll
        for (int d4 = 0; d4 < 8; ++d4) {
            float4 xv = *(const float4*)(x + d4 * 4);
            acc = fmaf(xv.x, w[d4 * 4 + 0], acc);
            acc = fmaf(xv.y, w[d4 * 4 + 1], acc);
            acc = fmaf(xv.z, w[d4 * 4 + 2], acc);
            acc = fmaf(xv.w, w[d4 * 4 + 3], acc);
        }
        acc += __shfl_xor(acc, 32);                     // combine d-halves
        if (h == 0) {
            __hip_bfloat16 hb = __float2bfloat16(acc);
            proj[((long)r * NN + n) * DDR + col] = *reinterpret_cast<unsigned short*>(&hb);
        }
    }
}

// ---- Kernel A': gather attention logits (16 lanes/edge), NO atomics ----
__global__ void k_attg(const unsigned* __restrict__ proj, const float* __restrict__ rel,
                       const int* __restrict__ src, const int* __restrict__ dst,
                       const int* __restrict__ et, float* __restrict__ att)
{
    long tid = (long)blockIdx.x * blockDim.x + threadIdx.x;
    int e = (int)(tid >> 4);
    int j = threadIdx.x & 15;
    if (e >= NE) return;
    int s = src[e], d = dst[e], r = et[e];
    uint2 tv = *(const uint2*)(proj + ((long)r * NN + s) * 32 + j * 2);
    uint2 hv = *(const uint2*)(proj + ((long)r * NN + d) * 32 + j * 2);
    float4 rv = *(const float4*)(rel + r * DDR + j * 4);
    float sum = bflo(tv.x) * tanhf(bflo(hv.x) + rv.x)
              + bfhi(tv.x) * tanhf(bfhi(hv.x) + rv.y)
              + bflo(tv.y) * tanhf(bflo(hv.y) + rv.z)
              + bfhi(tv.y) * tanhf(bfhi(hv.y) + rv.w);
#pragma unroll
    for (int off = 8; off; off >>= 1) sum += __shfl_xor(sum, off);
    if (j == 0) att[e] = sum;
}

// ---- CSR build: histogram -> single-block scan -> scatter ----
__global__ void k_hist(const int* __restrict__ dst, unsigned* __restrict__ cnt)
{
    int e = blockIdx.x * blockDim.x + threadIdx.x;
    if (e >= NE) return;
    atomicAdd(cnt + dst[e], 1u);
}

#define SCAN_T 1024
__global__ void k_scan(const unsigned* __restrict__ cnt, unsigned* __restrict__ base,
                       unsigned* __restrict__ curs)
{
    __shared__ unsigned lds[SCAN_T];
    int tid = threadIdx.x;
    const int chunk = (NN + SCAN_T - 1) / SCAN_T;
    int lo = tid * chunk;
    int hi = (lo + chunk < NN) ? lo + chunk : NN;
    unsigned s = 0;
    for (int i = lo; i < hi; ++i) s += cnt[i];
    lds[tid] = s;
    __syncthreads();
    for (int off = 1; off < SCAN_T; off <<= 1) {
        unsigned v = (tid >= off) ? lds[tid - off] : 0u;
        __syncthreads();
        lds[tid] += v;
        __syncthreads();
    }
    unsigned ex = (tid > 0) ? lds[tid - 1] : 0u;
    for (int i = lo; i < hi; ++i) {
        base[i] = ex; curs[i] = ex;
        ex += cnt[i];
    }
}

__global__ void k_scatter(const int* __restrict__ dst, unsigned* __restrict__ curs,
                          unsigned* __restrict__ eidx)
{
    int e = blockIdx.x * blockDim.x + threadIdx.x;
    if (e >= NE) return;
    unsigned pos = atomicAdd(curs + dst[e], 1u);
    eidx[pos] = (unsigned)e;
}

// ---- Fused edge-softmax + layer-0 aggregation: one wave per dst node ----
// Replaces segment-max atomicMax + expsum atomicAdd + 102M fp32 scatter
// atomics with register accumulation and ONE 256B row store per node.
__global__ void k_fused0(const float* __restrict__ emb, const float* __restrict__ att,
                         const int* __restrict__ src,
                         const unsigned* __restrict__ cnt, const unsigned* __restrict__ basep,
                         const unsigned* __restrict__ eidx,
                         float* __restrict__ Nh, float* __restrict__ invs,
                         float* __restrict__ mval)
{
    int gw = (int)(((long)blockIdx.x * blockDim.x + threadIdx.x) >> 6);
    int lane = threadIdx.x & 63;
    if (gw >= NN) return;
    int deg = (int)cnt[gw];
    if (deg == 0) {
        Nh[(long)gw * DD + lane] = 0.f;
        if (lane == 0) { invs[gw] = 0.f; mval[gw] = 0.f; }
        return;
    }
    long b = basep[gw];
    float m = -3.4e38f;
    for (int i = lane; i < deg; i += 64) m = fmaxf(m, att[eidx[b + i]]);
#pragma unroll
    for (int off = 32; off; off >>= 1) m = fmaxf(m, __shfl_xor(m, off));
    float acc = 0.f, s = 0.f;
    for (int i = 0; i < deg; ++i) {
        unsigned e = eidx[b + i];
        float ex = expf(att[e] - m);          // uniform across lanes
        int sv = src[e];
        acc = fmaf(emb[(long)sv * DD + lane], ex, acc);
        s += ex;
    }
    float inv = 1.f / s;
    Nh[(long)gw * DD + lane] = acc * inv;
    if (lane == 0) { invs[gw] = inv; mval[gw] = m; }
}

// ---- Layer-1 aggregation: 32-lane group per dst node, no atomics ----
__global__ void k_aggs1(const float* __restrict__ outb, const float* __restrict__ att,
                        const int* __restrict__ src,
                        const unsigned* __restrict__ cnt, const unsigned* __restrict__ basep,
                        const unsigned* __restrict__ eidx,
                        const float* __restrict__ invs, const float* __restrict__ mval,
                        float* __restrict__ Nh1)
{
    int g = (int)(((long)blockIdx.x * blockDim.x + threadIdx.x) >> 5);
    int lane = threadIdx.x & 31;
    if (g >= NN) return;
    int deg = (int)cnt[g];
    float acc = 0.f;
    if (deg > 0) {
        long b = basep[g];
        float inv = invs[g], m = mval[g];
        for (int i = 0; i < deg; ++i) {
            unsigned e = eidx[b + i];
            float a = expf(att[e] - m) * inv;
            int sv = src[e];
            acc = fmaf(outb[(long)sv * 112 + 64 + lane], a, acc);
        }
    }
    Nh1[(long)g * 32 + lane] = acc;
}

// ---- Kernel E: layer-0 node update; writes ego (cols 0..64) and h1 (cols 64..96) ----
__global__ void k_node0(const float* __restrict__ emb, const float* __restrict__ Nh,
                        const float* __restrict__ W1, const float* __restrict__ b1,
                        const float* __restrict__ W2, const float* __restrict__ b2,
                        float* __restrict__ out)
{
    int node = (int)((blockIdx.x * blockDim.x + threadIdx.x) >> 6);
    int lane = threadIdx.x & 63;
    if (node >= NN) return;
    const float* __restrict__ x  = emb + (long)node * DD;
    const float* __restrict__ nh = Nh + (long)node * DD;
    int j = lane & 31;
    const float* __restrict__ W = (lane < 32) ? (W1 + j * DD) : (W2 + j * DD);
    float acc = 0.f;
#pragma unroll 8
    for (int dd = 0; dd < DD; ++dd) {
        float xv = x[dd], nv = nh[dd];
        float v = (lane < 32) ? (xv + nv) : (xv * nv);
        acc = fmaf(v, W[dd], acc);
    }
    acc += (lane < 32) ? b1[j] : b2[j];
    acc = (acc >= 0.f) ? acc : 0.01f * acc;
    float other = __shfl_down(acc, 32);
    float h = acc + other;
    float ss = h * h;
#pragma unroll
    for (int off = 16; off; off >>= 1) ss += __shfl_xor(ss, off);
    float nrm = sqrtf(ss);
    float hn = h / fmaxf(nrm, 1e-12f);
    out[(long)node * 112 + lane] = x[lane];
    if (lane < 32) out[(long)node * 112 + 64 + j] = hn;
}

// ---- Kernel G: layer-1 node update; writes h2 (cols 96..112) ----
__global__ void k_node1(const float* __restrict__ outbuf, const float* __restrict__ Nh1,
                        const float* __restrict__ W1, const float* __restrict__ b1,
                        const float* __restrict__ W2, const float* __restrict__ b2,
                        float* __restrict__ out)
{
    int t = blockIdx.x * blockDim.x + threadIdx.x;
    int node = t >> 5;
    int lane = t & 31;
    if (node >= NN) return;
    const float* __restrict__ x  = outbuf + (long)node * 112 + 64;
    const float* __restrict__ nh = Nh1 + (long)node * 32;
    int j = lane & 15;
    const float* __restrict__ W = (lane < 16) ? (W1 + j * 32) : (W2 + j * 32);
    float acc = 0.f;
#pragma unroll 8
    for (int dd = 0; dd < 32; ++dd) {
        float xv = x[dd], nv = nh[dd];
        float v = (lane < 16) ? (xv + nv) : (xv * nv);
        acc = fmaf(v, W[dd], acc);
    }
    acc += (lane < 16) ? b1[j] : b2[j];
    acc = (acc >= 0.f) ? acc : 0.01f * acc;
    float other = __shfl_down(acc, 16, 32);
    float h = acc + other;
    float ss = h * h;
#pragma unroll
    for (int off = 8; off; off >>= 1) ss += __shfl_xor(ss, off);
    float nrm = sqrtf(ss);
    float hn = h / fmaxf(nrm, 1e-12f);
    if (lane < 16) out[(long)node * 112 + 96 + j] = hn;
}

// ================= fallback path (ws too small): round-1 kernels =================
__global__ void k_att(const float* __restrict__ emb, const float* __restrict__ rel,
                      const float* __restrict__ WR, const int* __restrict__ src,
                      const int* __restrict__ dst, const int* __restrict__ et,
                      float* __restrict__ att, unsigned* __restrict__ mkey)
{
    int e = (int)((blockIdx.x * blockDim.x + threadIdx.x) >> 6);
    int lane = threadIdx.x & 63;
    if (e >= NE) return;
    int s = src[e], d = dst[e], r = et[e];
    const float* __restrict__ es = emb + (long)s * DD;
    const float* __restrict__ eh = emb + (long)d * DD;
    const float* __restrict__ w  = WR + r * (DD * DDR) + lane;
    float at = 0.f, ah = 0.f;
#pragma unroll 8
    for (int dd = 0; dd < DD; ++dd) {
        float ws = w[dd * DDR];
        at = fmaf(es[dd], ws, at);
        ah = fmaf(eh[dd], ws, ah);
    }
    float term = at * tanhf(ah + rel[r * DDR + lane]);
#pragma unroll
    for (int off = 32; off; off >>= 1) term += __shfl_xor(term, off);
    if (lane == 0) {
        att[e] = term;
        atomicMax(mkey + d, enc_f(term));
    }
}

__global__ void k_expsum(const int* __restrict__ dst, float* __restrict__ att,
                         const unsigned* __restrict__ mkey, float* __restrict__ ssum)
{
    int e = blockIdx.x * blockDim.x + threadIdx.x;
    if (e >= NE) return;
    int d = dst[e];
    float ex = expf(att[e] - dec_f(mkey[d]));
    att[e] = ex;
    atomicAdd(ssum + d, ex);
}

__global__ void k_agg0(const float* __restrict__ emb, const int* __restrict__ src,
                       const int* __restrict__ dst, float* __restrict__ att,
                       const float* __restrict__ ssum, float* __restrict__ Nh)
{
    int e = (int)((blockIdx.x * blockDim.x + threadIdx.x) >> 6);
    int lane = threadIdx.x & 63;
    if (e >= NE) return;
    int s = src[e], d = dst[e];
    float a = att[e] / ssum[d];
    if (lane == 0) att[e] = a;
    float v = emb[(long)s * DD + lane] * a;
    atomicAdd(Nh + (long)d * DD + lane, v);
}

__global__ void k_agg1(const float* __restrict__ out, const int* __restrict__ src,
                       const int* __restrict__ dst, const float* __restrict__ att,
                       float* __restrict__ Nh1)
{
    int idx = blockIdx.x * blockDim.x + threadIdx.x;
    int e = idx >> 5;
    int j = idx & 31;
    if (e >= NE) return;
    int s = src[e], d = dst[e];
    float a = att[e];
    float v = out[(long)s * 112 + 64 + j] * a;
    atomicAdd(Nh1 + (long)d * 32 + j, v);
}

extern "C" void kernel_launch(void* const* d_in, const int* in_sizes, int n_in,
                              void* d_out, int out_size, void* d_ws, size_t ws_size,
                              hipStream_t stream) {
    const float* emb  = (const float*)d_in[0];
    const float* rel  = (const float*)d_in[1];
    const float* WR   = (const float*)d_in[2];
    const float* W1_0 = (const float*)d_in[3];
    const float* b1_0 = (const float*)d_in[4];
    const float* W2_0 = (const float*)d_in[5];
    const float* b2_0 = (const float*)d_in[6];
    const float* W1_1 = (const float*)d_in[7];
    const float* b1_1 = (const float*)d_in[8];
    const float* W2_1 = (const float*)d_in[9];
    const float* b2_1 = (const float*)d_in[10];
    const int*   src  = (const int*)d_in[11];
    const int*   dst  = (const int*)d_in[12];
    const int*   et   = (const int*)d_in[13];
    float* out = (float*)d_out;

    // main-path workspace (u32/f32 units):
    // [cnt NN][base NN][curs NN][invs NN][mval NN][Nh0 64NN][Nh1 32NN][att NE][eidx NE][proj bf16 NR*NN*64]
    unsigned* cnt  = (unsigned*)d_ws;
    unsigned* basep = cnt + NN;
    unsigned* curs = cnt + 2 * NN;
    float* invs = (float*)d_ws + 3 * NN;
    float* mval = (float*)d_ws + 4 * NN;
    float* Nh0  = (float*)d_ws + 5 * NN;
    float* Nh1  = (float*)d_ws + (5 + DD) * NN;
    float* att  = (float*)d_ws + (5 + DD + 32) * NN;
    unsigned* eidx = (unsigned*)(att + NE);
    unsigned* proj = eidx + NE;

    size_t need = ((size_t)(5 + DD + 32) * NN + 2 * (size_t)NE) * 4
                + (size_t)NN * NR * DDR * 2;

    if (ws_size >= need) {
        hipMemsetAsync(d_ws, 0, (size_t)NN * sizeof(unsigned), stream);  // cnt only
        k_hist<<<dim3((NE + 255) / 256), dim3(256), 0, stream>>>(dst, cnt);
        k_proj3<<<dim3((NN + 31) / 32, NR), dim3(256), 0, stream>>>(
            emb, WR, (unsigned short*)proj);
        k_attg<<<dim3((int)(((long)NE * 16 + 255) / 256)), dim3(256), 0, stream>>>(
            proj, rel, src, dst, et, att);
        k_scan<<<dim3(1), dim3(SCAN_T), 0, stream>>>(cnt, basep, curs);
        k_scatter<<<dim3((NE + 255) / 256), dim3(256), 0, stream>>>(dst, curs, eidx);
        k_fused0<<<dim3((int)(((long)NN * 64 + 255) / 256)), dim3(256), 0, stream>>>(
            emb, att, src, cnt, basep, eidx, Nh0, invs, mval);
        k_node0<<<dim3((int)(((long)NN * 64 + 255) / 256)), dim3(256), 0, stream>>>(
            emb, Nh0, W1_0, b1_0, W2_0, b2_0, out);
        k_aggs1<<<dim3((int)(((long)NN * 32 + 255) / 256)), dim3(256), 0, stream>>>(
            out, att, src, cnt, basep, eidx, invs, mval, Nh1);
        k_node1<<<dim3((int)(((long)NN * 32 + 255) / 256)), dim3(256), 0, stream>>>(
            out, Nh1, W1_1, b1_1, W2_1, b2_1, out);
    } else {
        // fallback: round-1 atomic pipeline, old layout
        unsigned* mkey = (unsigned*)d_ws;
        float* ssum = (float*)d_ws + NN;
        float* fNh0 = (float*)d_ws + 2 * NN;
        float* fNh1 = (float*)d_ws + (2 + DD) * NN;
        float* fatt = (float*)d_ws + (2 + DD + 32) * NN;
        hipMemsetAsync(d_ws, 0, (size_t)(2 + DD + 32) * NN * sizeof(float), stream);
        k_att<<<dim3((int)(((long)NE * 64 + 255) / 256)), dim3(256), 0, stream>>>(
            emb, rel, WR, src, dst, et, fatt, mkey);
        k_expsum<<<dim3((NE + 255) / 256), dim3(256), 0, stream>>>(dst, fatt, mkey, ssum);
        k_agg0<<<dim3((int)(((long)NE * 64 + 255) / 256)), dim3(256), 0, stream>>>(
            emb, src, dst, fatt, ssum, fNh0);
        k_node0<<<dim3((int)(((long)NN * 64 + 255) / 256)), dim3(256), 0, stream>>>(
            emb, fNh0, W1_0, b1_0, W2_0, b2_0, out);
        k_agg1<<<dim3((int)(((long)NE * 32 + 255) / 256)), dim3(256), 0, stream>>>(
            out, src, dst, fatt, fNh1);
        k_node1<<<dim3((int)(((long)NN * 32 + 255) / 256)), dim3(256), 0, stream>>>(
            out, fNh1, W1_1, b1_1, W2_1, b2_1, out);
    }
}

// Round 9
// 939.588 us; speedup vs baseline: 1.7139x; 1.7139x over previous
//
#include <hip/hip_runtime.h>
#include <hip/hip_bf16.h>
#include <math.h>

#define NN 100000
#define NE 1600000
#define NR 8
#define DD 64
#define DDR 64

typedef __attribute__((ext_vector_type(8))) short bf8v;   // 8 x bf16 (4 VGPRs)
typedef __attribute__((ext_vector_type(4))) float f4v;    // MFMA accumulator

// ---- order-preserving float<->uint encoding (fallback path only) ----
__device__ __forceinline__ unsigned enc_f(float f) {
    unsigned u = __float_as_uint(f);
    return (u & 0x80000000u) ? ~u : (u | 0x80000000u);
}
__device__ __forceinline__ float dec_f(unsigned u) {
    return (u & 0x80000000u) ? __uint_as_float(u & 0x7FFFFFFFu) : __uint_as_float(~u);
}

__device__ __forceinline__ float bflo(unsigned u) { return __uint_as_float(u << 16); }
__device__ __forceinline__ float bfhi(unsigned u) { return __uint_as_float(u & 0xFFFF0000u); }
__device__ __forceinline__ short f2bfs(float x) {
    __hip_bfloat16 h = __float2bfloat16(x);
    return *reinterpret_cast<short*>(&h);
}

// ---- Kernel PM: proj[r][n][c] = emb[n] @ W_R[r] via MFMA ----
// Block 256 = 4 waves: wave = (node-half nh2 = wv>>1, col-half = wv&1).
// Each wave: holds 4 B-frags (W cols, 16 VGPRs) across a 4-tile node loop;
// per 16-node tile: 2 A-frags from fp32 emb (cvt to bf16), 4 mfma, store bf16.
// Layouts (gfx950 16x16x32 bf16): A: row=l&15, k=(l>>4)*8+j; B: col=l&15,
// k=(l>>4)*8+j; D: col=l&15, row=(l>>4)*4+reg [m89-verified].
__global__ void __launch_bounds__(256)
k_projm(const float* __restrict__ emb, const float* __restrict__ WR,
        unsigned short* __restrict__ proj)
{
    int t = threadIdx.x;
    int wv = t >> 6, l = t & 63;
    int lo = l & 15, hi = l >> 4;                 // hi in 0..3
    int r = blockIdx.y;
    int colbase = (wv & 1) * 32;
    int nwbase = blockIdx.x * 128 + (wv >> 1) * 64;

    // B fragments: (ct in {0,1} col-tile, kh in {0,1} K-half)
    const float* __restrict__ wb = WR + (long)r * (DD * DDR) + (hi * 8) * DDR + colbase + lo;
    bf8v B00, B01, B10, B11;
#pragma unroll
    for (int j = 0; j < 8; ++j) {
        B00[j] = f2bfs(wb[(0 * 32 + j) * DDR + 0]);
        B01[j] = f2bfs(wb[(1 * 32 + j) * DDR + 0]);
        B10[j] = f2bfs(wb[(0 * 32 + j) * DDR + 16]);
        B11[j] = f2bfs(wb[(1 * 32 + j) * DDR + 16]);
    }

    for (int nt = 0; nt < 4; ++nt) {
        int nb = nwbase + nt * 16;
        int arow = nb + lo;
        float4 xa0 = make_float4(0.f, 0.f, 0.f, 0.f), xa1 = xa0, xb0 = xa0, xb1 = xa0;
        if (arow < NN) {
            const float* __restrict__ xr = emb + (long)arow * DD + hi * 8;
            xa0 = *(const float4*)(xr);
            xa1 = *(const float4*)(xr + 4);
            xb0 = *(const float4*)(xr + 32);
            xb1 = *(const float4*)(xr + 36);
        }
        bf8v A0, A1;
        A0[0] = f2bfs(xa0.x); A0[1] = f2bfs(xa0.y); A0[2] = f2bfs(xa0.z); A0[3] = f2bfs(xa0.w);
        A0[4] = f2bfs(xa1.x); A0[5] = f2bfs(xa1.y); A0[6] = f2bfs(xa1.z); A0[7] = f2bfs(xa1.w);
        A1[0] = f2bfs(xb0.x); A1[1] = f2bfs(xb0.y); A1[2] = f2bfs(xb0.z); A1[3] = f2bfs(xb0.w);
        A1[4] = f2bfs(xb1.x); A1[5] = f2bfs(xb1.y); A1[6] = f2bfs(xb1.z); A1[7] = f2bfs(xb1.w);

        f4v acc0 = {0.f, 0.f, 0.f, 0.f}, acc1 = {0.f, 0.f, 0.f, 0.f};
        acc0 = __builtin_amdgcn_mfma_f32_16x16x32_bf16(A0, B00, acc0, 0, 0, 0);
        acc0 = __builtin_amdgcn_mfma_f32_16x16x32_bf16(A1, B01, acc0, 0, 0, 0);
        acc1 = __builtin_amdgcn_mfma_f32_16x16x32_bf16(A0, B10, acc1, 0, 0, 0);
        acc1 = __builtin_amdgcn_mfma_f32_16x16x32_bf16(A1, B11, acc1, 0, 0, 0);

#pragma unroll
        for (int i = 0; i < 4; ++i) {
            int rr = nb + hi * 4 + i;
            if (rr < NN) {
                long obase = ((long)r * NN + rr) * DDR + colbase + lo;
                proj[obase]      = (unsigned short)f2bfs(acc0[i]);
                proj[obase + 16] = (unsigned short)f2bfs(acc1[i]);
            }
        }
    }
}

// ---- Kernel A': gather attention logits (16 lanes/edge), NO atomics ----
__global__ void k_attg(const unsigned* __restrict__ proj, const float* __restrict__ rel,
                       const int* __restrict__ src, const int* __restrict__ dst,
                       const int* __restrict__ et, float* __restrict__ att)
{
    long tid = (long)blockIdx.x * blockDim.x + threadIdx.x;
    int e = (int)(tid >> 4);
    int j = threadIdx.x & 15;
    if (e >= NE) return;
    int s = src[e], d = dst[e], r = et[e];
    uint2 tv = *(const uint2*)(proj + ((long)r * NN + s) * 32 + j * 2);
    uint2 hv = *(const uint2*)(proj + ((long)r * NN + d) * 32 + j * 2);
    float4 rv = *(const float4*)(rel + r * DDR + j * 4);
    float sum = bflo(tv.x) * tanhf(bflo(hv.x) + rv.x)
              + bfhi(tv.x) * tanhf(bfhi(hv.x) + rv.y)
              + bflo(tv.y) * tanhf(bflo(hv.y) + rv.z)
              + bfhi(tv.y) * tanhf(bfhi(hv.y) + rv.w);
#pragma unroll
    for (int off = 8; off; off >>= 1) sum += __shfl_xor(sum, off);
    if (j == 0) att[e] = sum;
}

// ---- CSR build: histogram -> per-wave scan + global cursor -> scatter ----
__global__ void k_hist(const int* __restrict__ dst, unsigned* __restrict__ cnt)
{
    int e = blockIdx.x * blockDim.x + threadIdx.x;
    if (e >= NE) return;
    atomicAdd(cnt + dst[e], 1u);
}

// Unordered exclusive offsets: wave-local shfl scan + one atomicAdd per wave.
// (CSR group ORDER is irrelevant; only disjoint contiguous ranges matter.)
__global__ void k_base(const unsigned* __restrict__ cnt, unsigned* __restrict__ gcur,
                       unsigned* __restrict__ base, unsigned* __restrict__ curs)
{
    int i = blockIdx.x * blockDim.x + threadIdx.x;
    int lane = threadIdx.x & 63;
    unsigned v = (i < NN) ? cnt[i] : 0u;
    unsigned p = v;
#pragma unroll
    for (int off = 1; off < 64; off <<= 1) {
        unsigned q = __shfl_up(p, off);
        if (lane >= off) p += q;
    }
    unsigned tot = __shfl(p, 63);
    unsigned gb = 0;
    if (lane == 0) gb = atomicAdd(gcur, tot);
    gb = __shfl(gb, 0);
    if (i < NN) {
        unsigned b = gb + p - v;
        base[i] = b;
        curs[i] = b;
    }
}

__global__ void k_scatter(const int* __restrict__ dst, unsigned* __restrict__ curs,
                          unsigned* __restrict__ eidx)
{
    int e = blockIdx.x * blockDim.x + threadIdx.x;
    if (e >= NE) return;
    unsigned pos = atomicAdd(curs + dst[e], 1u);
    eidx[pos] = (unsigned)e;
}

// ---- Fused edge-softmax + layer-0 aggregation: one wave per dst node ----
// Fast path (deg<=64): ONE coalesced lane-parallel gather of (eidx,att,src),
// softmax via shfl reductions, accumulate loop uses shfl broadcasts (no
// re-gathers). Also writes normalized a[e] back into att for layer 1.
__global__ void k_fused0(const float* __restrict__ emb, float* __restrict__ att,
                         const int* __restrict__ src,
                         const unsigned* __restrict__ cnt, const unsigned* __restrict__ basep,
                         const unsigned* __restrict__ eidx,
                         float* __restrict__ Nh)
{
    int gw = (int)(((long)blockIdx.x * blockDim.x + threadIdx.x) >> 6);
    int lane = threadIdx.x & 63;
    if (gw >= NN) return;
    int deg = (int)cnt[gw];
    if (deg == 0) {
        Nh[(long)gw * DD + lane] = 0.f;
        return;
    }
    long b = basep[gw];
    if (deg <= 64) {
        unsigned e = 0; float atv = -3.4e38f; int sv = 0;
        if (lane < deg) {
            e = eidx[b + lane];
            atv = att[e];
            sv = src[e];
        }
        float m = atv;
#pragma unroll
        for (int off = 32; off; off >>= 1) m = fmaxf(m, __shfl_xor(m, off));
        float exv = (lane < deg) ? expf(atv - m) : 0.f;
        float s = exv;
#pragma unroll
        for (int off = 32; off; off >>= 1) s += __shfl_xor(s, off);
        float inv = 1.f / s;
        if (lane < deg) att[e] = exv * inv;         // normalized weight for layer 1
        float acc = 0.f;
        for (int i = 0; i < deg; ++i) {
            float a = __shfl(exv, i);
            int si = __shfl(sv, i);
            acc = fmaf(emb[(long)si * DD + lane], a, acc);
        }
        Nh[(long)gw * DD + lane] = acc * inv;
    } else {
        float m = -3.4e38f;
        for (int i = lane; i < deg; i += 64) m = fmaxf(m, att[eidx[b + i]]);
#pragma unroll
        for (int off = 32; off; off >>= 1) m = fmaxf(m, __shfl_xor(m, off));
        float s = 0.f, acc = 0.f;
        for (int i = 0; i < deg; ++i) {
            unsigned e = eidx[b + i];
            float ex = expf(att[e] - m);
            s += ex;
            acc = fmaf(emb[(long)src[e] * DD + lane], ex, acc);
        }
        float inv = 1.f / s;
        for (int i = lane; i < deg; i += 64) {
            unsigned e = eidx[b + i];
            att[e] = expf(att[e] - m) * inv;
        }
        Nh[(long)gw * DD + lane] = acc * inv;
    }
}

// ---- Layer-1 aggregation: 32-lane group per dst, a[e] precomputed in att ----
__global__ void k_aggs1(const float* __restrict__ outb, const float* __restrict__ att,
                        const int* __restrict__ src,
                        const unsigned* __restrict__ cnt, const unsigned* __restrict__ basep,
                        const unsigned* __restrict__ eidx,
                        float* __restrict__ Nh1)
{
    int g = (int)(((long)blockIdx.x * blockDim.x + threadIdx.x) >> 5);
    int l5 = threadIdx.x & 31;
    if (g >= NN) return;
    int deg = (int)cnt[g];
    float acc = 0.f;
    if (deg > 0) {
        long b = basep[g];
        unsigned e = 0; float a = 0.f; int sv = 0;
        if (l5 < deg) {
            e = eidx[b + l5];
            a = att[e];
            sv = src[e];
        }
        int dmin = (deg < 32) ? deg : 32;
        for (int i = 0; i < dmin; ++i) {
            float ai = __shfl(a, i, 32);
            int si = __shfl(sv, i, 32);
            acc = fmaf(outb[(long)si * 112 + 64 + l5], ai, acc);
        }
        for (int i = 32; i < deg; ++i) {
            unsigned e2 = eidx[b + i];
            float a2 = att[e2];
            int s2 = src[e2];
            acc = fmaf(outb[(long)s2 * 112 + 64 + l5], a2, acc);
        }
    }
    Nh1[(long)g * 32 + l5] = acc;
}

// ---- Kernel E: layer-0 node update; writes ego (cols 0..64) and h1 (cols 64..96) ----
__global__ void k_node0(const float* __restrict__ emb, const float* __restrict__ Nh,
                        const float* __restrict__ W1, const float* __restrict__ b1,
                        const float* __restrict__ W2, const float* __restrict__ b2,
                        float* __restrict__ out)
{
    int node = (int)((blockIdx.x * blockDim.x + threadIdx.x) >> 6);
    int lane = threadIdx.x & 63;
    if (node >= NN) return;
    const float* __restrict__ x  = emb + (long)node * DD;
    const float* __restrict__ nh = Nh + (long)node * DD;
    int j = lane & 31;
    const float* __restrict__ W = (lane < 32) ? (W1 + j * DD) : (W2 + j * DD);
    float acc = 0.f;
#pragma unroll 8
    for (int dd = 0; dd < DD; ++dd) {
        float xv = x[dd], nv = nh[dd];
        float v = (lane < 32) ? (xv + nv) : (xv * nv);
        acc = fmaf(v, W[dd], acc);
    }
    acc += (lane < 32) ? b1[j] : b2[j];
    acc = (acc >= 0.f) ? acc : 0.01f * acc;
    float other = __shfl_down(acc, 32);
    float h = acc + other;
    float ss = h * h;
#pragma unroll
    for (int off = 16; off; off >>= 1) ss += __shfl_xor(ss, off);
    float nrm = sqrtf(ss);
    float hn = h / fmaxf(nrm, 1e-12f);
    out[(long)node * 112 + lane] = x[lane];
    if (lane < 32) out[(long)node * 112 + 64 + j] = hn;
}

// ---- Kernel G: layer-1 node update; writes h2 (cols 96..112) ----
__global__ void k_node1(const float* __restrict__ outbuf, const float* __restrict__ Nh1,
                        const float* __restrict__ W1, const float* __restrict__ b1,
                        const float* __restrict__ W2, const float* __restrict__ b2,
                        float* __restrict__ out)
{
    int t = blockIdx.x * blockDim.x + threadIdx.x;
    int node = t >> 5;
    int lane = t & 31;
    if (node >= NN) return;
    const float* __restrict__ x  = outbuf + (long)node * 112 + 64;
    const float* __restrict__ nh = Nh1 + (long)node * 32;
    int j = lane & 15;
    const float* __restrict__ W = (lane < 16) ? (W1 + j * 32) : (W2 + j * 32);
    float acc = 0.f;
#pragma unroll 8
    for (int dd = 0; dd < 32; ++dd) {
        float xv = x[dd], nv = nh[dd];
        float v = (lane < 16) ? (xv + nv) : (xv * nv);
        acc = fmaf(v, W[dd], acc);
    }
    acc += (lane < 16) ? b1[j] : b2[j];
    acc = (acc >= 0.f) ? acc : 0.01f * acc;
    float other = __shfl_down(acc, 16, 32);
    float h = acc + other;
    float ss = h * h;
#pragma unroll
    for (int off = 8; off; off >>= 1) ss += __shfl_xor(ss, off);
    float nrm = sqrtf(ss);
    float hn = h / fmaxf(nrm, 1e-12f);
    if (lane < 16) out[(long)node * 112 + 96 + j] = hn;
}

// ================= fallback path (ws too small): round-1 kernels =================
__global__ void k_att(const float* __restrict__ emb, const float* __restrict__ rel,
                      const float* __restrict__ WR, const int* __restrict__ src,
                      const int* __restrict__ dst, const int* __restrict__ et,
                      float* __restrict__ att, unsigned* __restrict__ mkey)
{
    int e = (int)((blockIdx.x * blockDim.x + threadIdx.x) >> 6);
    int lane = threadIdx.x & 63;
    if (e >= NE) return;
    int s = src[e], d = dst[e], r = et[e];
    const float* __restrict__ es = emb + (long)s * DD;
    const float* __restrict__ eh = emb + (long)d * DD;
    const float* __restrict__ w  = WR + r * (DD * DDR) + lane;
    float at = 0.f, ah = 0.f;
#pragma unroll 8
    for (int dd = 0; dd < DD; ++dd) {
        float ws = w[dd * DDR];
        at = fmaf(es[dd], ws, at);
        ah = fmaf(eh[dd], ws, ah);
    }
    float term = at * tanhf(ah + rel[r * DDR + lane]);
#pragma unroll
    for (int off = 32; off; off >>= 1) term += __shfl_xor(term, off);
    if (lane == 0) {
        att[e] = term;
        atomicMax(mkey + d, enc_f(term));
    }
}

__global__ void k_expsum(const int* __restrict__ dst, float* __restrict__ att,
                         const unsigned* __restrict__ mkey, float* __restrict__ ssum)
{
    int e = blockIdx.x * blockDim.x + threadIdx.x;
    if (e >= NE) return;
    int d = dst[e];
    float ex = expf(att[e] - dec_f(mkey[d]));
    att[e] = ex;
    atomicAdd(ssum + d, ex);
}

__global__ void k_agg0(const float* __restrict__ emb, const int* __restrict__ src,
                       const int* __restrict__ dst, float* __restrict__ att,
                       const float* __restrict__ ssum, float* __restrict__ Nh)
{
    int e = (int)((blockIdx.x * blockDim.x + threadIdx.x) >> 6);
    int lane = threadIdx.x & 63;
    if (e >= NE) return;
    int s = src[e], d = dst[e];
    float a = att[e] / ssum[d];
    if (lane == 0) att[e] = a;
    float v = emb[(long)s * DD + lane] * a;
    atomicAdd(Nh + (long)d * DD + lane, v);
}

__global__ void k_agg1(const float* __restrict__ out, const int* __restrict__ src,
                       const int* __restrict__ dst, const float* __restrict__ att,
                       float* __restrict__ Nh1)
{
    int idx = blockIdx.x * blockDim.x + threadIdx.x;
    int e = idx >> 5;
    int j = idx & 31;
    if (e >= NE) return;
    int s = src[e], d = dst[e];
    float a = att[e];
    float v = out[(long)s * 112 + 64 + j] * a;
    atomicAdd(Nh1 + (long)d * 32 + j, v);
}

extern "C" void kernel_launch(void* const* d_in, const int* in_sizes, int n_in,
                              void* d_out, int out_size, void* d_ws, size_t ws_size,
                              hipStream_t stream) {
    const float* emb  = (const float*)d_in[0];
    const float* rel  = (const float*)d_in[1];
    const float* WR   = (const float*)d_in[2];
    const float* W1_0 = (const float*)d_in[3];
    const float* b1_0 = (const float*)d_in[4];
    const float* W2_0 = (const float*)d_in[5];
    const float* b2_0 = (const float*)d_in[6];
    const float* W1_1 = (const float*)d_in[7];
    const float* b1_1 = (const float*)d_in[8];
    const float* W2_1 = (const float*)d_in[9];
    const float* b2_1 = (const float*)d_in[10];
    const int*   src  = (const int*)d_in[11];
    const int*   dst  = (const int*)d_in[12];
    const int*   et   = (const int*)d_in[13];
    float* out = (float*)d_out;

    // main-path workspace (4B units):
    // [cnt NN][gcur 64][base NN][curs NN][Nh0 64NN][Nh1 32NN][att NE][eidx NE][proj bf16 NR*NN*64]
    unsigned* cnt   = (unsigned*)d_ws;
    unsigned* gcur  = cnt + NN;
    unsigned* basep = cnt + NN + 64;
    unsigned* curs  = cnt + 2 * NN + 64;
    float* Nh0  = (float*)d_ws + 3 * NN + 64;
    float* Nh1  = (float*)d_ws + (3 + DD) * NN + 64;
    float* att  = (float*)d_ws + (3 + DD + 32) * NN + 64;
    unsigned* eidx = (unsigned*)(att + NE);
    unsigned* proj = eidx + NE;

    size_t need = ((size_t)(3 + DD + 32) * NN + 64 + 2 * (size_t)NE) * 4
                + (size_t)NN * NR * DDR * 2;

    if (ws_size >= need) {
        hipMemsetAsync(d_ws, 0, (size_t)(NN + 64) * sizeof(unsigned), stream);  // cnt + gcur
        k_hist<<<dim3((NE + 255) / 256), dim3(256), 0, stream>>>(dst, cnt);
        k_projm<<<dim3((NN + 127) / 128, NR), dim3(256), 0, stream>>>(
            emb, WR, (unsigned short*)proj);
        k_attg<<<dim3((int)(((long)NE * 16 + 255) / 256)), dim3(256), 0, stream>>>(
            proj, rel, src, dst, et, att);
        k_base<<<dim3((NN + 255) / 256), dim3(256), 0, stream>>>(cnt, gcur, basep, curs);
        k_scatter<<<dim3((NE + 255) / 256), dim3(256), 0, stream>>>(dst, curs, eidx);
        k_fused0<<<dim3((int)(((long)NN * 64 + 255) / 256)), dim3(256), 0, stream>>>(
            emb, att, src, cnt, basep, eidx, Nh0);
        k_node0<<<dim3((int)(((long)NN * 64 + 255) / 256)), dim3(256), 0, stream>>>(
            emb, Nh0, W1_0, b1_0, W2_0, b2_0, out);
        k_aggs1<<<dim3((int)(((long)NN * 32 + 255) / 256)), dim3(256), 0, stream>>>(
            out, att, src, cnt, basep, eidx, Nh1);
        k_node1<<<dim3((int)(((long)NN * 32 + 255) / 256)), dim3(256), 0, stream>>>(
            out, Nh1, W1_1, b1_1, W2_1, b2_1, out);
    } else {
        // fallback: round-1 atomic pipeline, old layout
        unsigned* mkey = (unsigned*)d_ws;
        float* ssum = (float*)d_ws + NN;
        float* fNh0 = (float*)d_ws + 2 * NN;
        float* fNh1 = (float*)d_ws + (2 + DD) * NN;
        float* fatt = (float*)d_ws + (2 + DD + 32) * NN;
        hipMemsetAsync(d_ws, 0, (size_t)(2 + DD + 32) * NN * sizeof(float), stream);
        k_att<<<dim3((int)(((long)NE * 64 + 255) / 256)), dim3(256), 0, stream>>>(
            emb, rel, WR, src, dst, et, fatt, mkey);
        k_expsum<<<dim3((NE + 255) / 256), dim3(256), 0, stream>>>(dst, fatt, mkey, ssum);
        k_agg0<<<dim3((int)(((long)NE * 64 + 255) / 256)), dim3(256), 0, stream>>>(
            emb, src, dst, fatt, ssum, fNh0);
        k_node0<<<dim3((int)(((long)NN * 64 + 255) / 256)), dim3(256), 0, stream>>>(
            emb, fNh0, W1_0, b1_0, W2_0, b2_0, out);
        k_agg1<<<dim3((int)(((long)NE * 32 + 255) / 256)), dim3(256), 0, stream>>>(
            out, src, dst, fatt, fNh1);
        k_node1<<<dim3((int)(((long)NN * 32 + 255) / 256)), dim3(256), 0, stream>>>(
            out, fNh1, W1_1, b1_1, W2_1, b2_1, out);
    }
}

// Round 11
// 740.655 us; speedup vs baseline: 2.1742x; 1.2686x over previous
//
#include <hip/hip_runtime.h>
#include <hip/hip_bf16.h>
#include <math.h>

#define NN 100000
#define NE 1600000
#define NR 8
#define DD 64
#define DDR 64

typedef __attribute__((ext_vector_type(8))) short bf8v;   // 8 x bf16 (4 VGPRs)
typedef __attribute__((ext_vector_type(4))) float f4v;    // MFMA accumulator

// ---- order-preserving float<->uint encoding (fallback path only) ----
__device__ __forceinline__ unsigned enc_f(float f) {
    unsigned u = __float_as_uint(f);
    return (u & 0x80000000u) ? ~u : (u | 0x80000000u);
}
__device__ __forceinline__ float dec_f(unsigned u) {
    return (u & 0x80000000u) ? __uint_as_float(u & 0x7FFFFFFFu) : __uint_as_float(~u);
}

__device__ __forceinline__ float bflo(unsigned u) { return __uint_as_float(u << 16); }
__device__ __forceinline__ float bfhi(unsigned u) { return __uint_as_float(u & 0xFFFF0000u); }
__device__ __forceinline__ short f2bfs(float x) {
    __hip_bfloat16 h = __float2bfloat16(x);
    return *reinterpret_cast<short*>(&h);
}

// ---- Kernel PM: proj[r][n][c] = emb[n] @ W_R[r] via MFMA ----
__global__ void __launch_bounds__(256)
k_projm(const float* __restrict__ emb, const float* __restrict__ WR,
        unsigned short* __restrict__ proj)
{
    int t = threadIdx.x;
    int wv = t >> 6, l = t & 63;
    int lo = l & 15, hi = l >> 4;
    int r = blockIdx.y;
    int colbase = (wv & 1) * 32;
    int nwbase = blockIdx.x * 128 + (wv >> 1) * 64;

    const float* __restrict__ wb = WR + (long)r * (DD * DDR) + (hi * 8) * DDR + colbase + lo;
    bf8v B00, B01, B10, B11;
#pragma unroll
    for (int j = 0; j < 8; ++j) {
        B00[j] = f2bfs(wb[(0 * 32 + j) * DDR + 0]);
        B01[j] = f2bfs(wb[(1 * 32 + j) * DDR + 0]);
        B10[j] = f2bfs(wb[(0 * 32 + j) * DDR + 16]);
        B11[j] = f2bfs(wb[(1 * 32 + j) * DDR + 16]);
    }

    for (int nt = 0; nt < 4; ++nt) {
        int nb = nwbase + nt * 16;
        int arow = nb + lo;
        float4 xa0 = make_float4(0.f, 0.f, 0.f, 0.f), xa1 = xa0, xb0 = xa0, xb1 = xa0;
        if (arow < NN) {
            const float* __restrict__ xr = emb + (long)arow * DD + hi * 8;
            xa0 = *(const float4*)(xr);
            xa1 = *(const float4*)(xr + 4);
            xb0 = *(const float4*)(xr + 32);
            xb1 = *(const float4*)(xr + 36);
        }
        bf8v A0, A1;
        A0[0] = f2bfs(xa0.x); A0[1] = f2bfs(xa0.y); A0[2] = f2bfs(xa0.z); A0[3] = f2bfs(xa0.w);
        A0[4] = f2bfs(xa1.x); A0[5] = f2bfs(xa1.y); A0[6] = f2bfs(xa1.z); A0[7] = f2bfs(xa1.w);
        A1[0] = f2bfs(xb0.x); A1[1] = f2bfs(xb0.y); A1[2] = f2bfs(xb0.z); A1[3] = f2bfs(xb0.w);
        A1[4] = f2bfs(xb1.x); A1[5] = f2bfs(xb1.y); A1[6] = f2bfs(xb1.z); A1[7] = f2bfs(xb1.w);

        f4v acc0 = {0.f, 0.f, 0.f, 0.f}, acc1 = {0.f, 0.f, 0.f, 0.f};
        acc0 = __builtin_amdgcn_mfma_f32_16x16x32_bf16(A0, B00, acc0, 0, 0, 0);
        acc0 = __builtin_amdgcn_mfma_f32_16x16x32_bf16(A1, B01, acc0, 0, 0, 0);
        acc1 = __builtin_amdgcn_mfma_f32_16x16x32_bf16(A0, B10, acc1, 0, 0, 0);
        acc1 = __builtin_amdgcn_mfma_f32_16x16x32_bf16(A1, B11, acc1, 0, 0, 0);

#pragma unroll
        for (int i = 0; i < 4; ++i) {
            int rr = nb + hi * 4 + i;
            if (rr < NN) {
                long obase = ((long)r * NN + rr) * DDR + colbase + lo;
                proj[obase]      = (unsigned short)f2bfs(acc0[i]);
                proj[obase + 16] = (unsigned short)f2bfs(acc1[i]);
            }
        }
    }
}

// ---- Kernel A': gather attention logits (16 lanes/edge), NO atomics ----
__global__ void k_attg(const unsigned* __restrict__ proj, const float* __restrict__ rel,
                       const int* __restrict__ src, const int* __restrict__ dst,
                       const int* __restrict__ et, float* __restrict__ att)
{
    long tid = (long)blockIdx.x * blockDim.x + threadIdx.x;
    int e = (int)(tid >> 4);
    int j = threadIdx.x & 15;
    if (e >= NE) return;
    int s = src[e], d = dst[e], r = et[e];
    uint2 tv = *(const uint2*)(proj + ((long)r * NN + s) * 32 + j * 2);
    uint2 hv = *(const uint2*)(proj + ((long)r * NN + d) * 32 + j * 2);
    float4 rv = *(const float4*)(rel + r * DDR + j * 4);
    float sum = bflo(tv.x) * tanhf(bflo(hv.x) + rv.x)
              + bfhi(tv.x) * tanhf(bfhi(hv.x) + rv.y)
              + bflo(tv.y) * tanhf(bflo(hv.y) + rv.z)
              + bfhi(tv.y) * tanhf(bfhi(hv.y) + rv.w);
#pragma unroll
    for (int off = 8; off; off >>= 1) sum += __shfl_xor(sum, off);
    if (j == 0) att[e] = sum;
}

// ---- CSR build: histogram -> per-wave scan + global cursor -> scatter ----
__global__ void k_hist(const int* __restrict__ dst, unsigned* __restrict__ cnt)
{
    int e = blockIdx.x * blockDim.x + threadIdx.x;
    if (e >= NE) return;
    atomicAdd(cnt + dst[e], 1u);
}

__global__ void k_base(const unsigned* __restrict__ cnt, unsigned* __restrict__ gcur,
                       unsigned* __restrict__ base, unsigned* __restrict__ curs)
{
    int i = blockIdx.x * blockDim.x + threadIdx.x;
    int lane = threadIdx.x & 63;
    unsigned v = (i < NN) ? cnt[i] : 0u;
    unsigned p = v;
#pragma unroll
    for (int off = 1; off < 64; off <<= 1) {
        unsigned q = __shfl_up(p, off);
        if (lane >= off) p += q;
    }
    unsigned tot = __shfl(p, 63);
    unsigned gb = 0;
    if (lane == 0) gb = atomicAdd(gcur, tot);
    gb = __shfl(gb, 0);
    if (i < NN) {
        unsigned b = gb + p - v;
        base[i] = b;
        curs[i] = b;
    }
}

__global__ void k_scatter(const int* __restrict__ dst, unsigned* __restrict__ curs,
                          unsigned* __restrict__ eidx)
{
    int e = blockIdx.x * blockDim.x + threadIdx.x;
    if (e >= NE) return;
    unsigned pos = atomicAdd(curs + dst[e], 1u);
    eidx[pos] = (unsigned)e;
}

// ---- Fused edge-softmax + layer-0 aggregation: one wave per dst node ----
__global__ void k_fused0(const float* __restrict__ emb, float* __restrict__ att,
                         const int* __restrict__ src,
                         const unsigned* __restrict__ cnt, const unsigned* __restrict__ basep,
                         const unsigned* __restrict__ eidx,
                         float* __restrict__ Nh)
{
    int gw = (int)(((long)blockIdx.x * blockDim.x + threadIdx.x) >> 6);
    int lane = threadIdx.x & 63;
    if (gw >= NN) return;
    int deg = (int)cnt[gw];
    if (deg == 0) {
        Nh[(long)gw * DD + lane] = 0.f;
        return;
    }
    long b = basep[gw];
    if (deg <= 64) {
        unsigned e = 0; float atv = -3.4e38f; int sv = 0;
        if (lane < deg) {
            e = eidx[b + lane];
            atv = att[e];
            sv = src[e];
        }
        float m = atv;
#pragma unroll
        for (int off = 32; off; off >>= 1) m = fmaxf(m, __shfl_xor(m, off));
        float exv = (lane < deg) ? expf(atv - m) : 0.f;
        float s = exv;
#pragma unroll
        for (int off = 32; off; off >>= 1) s += __shfl_xor(s, off);
        float inv = 1.f / s;
        if (lane < deg) att[e] = exv * inv;
        float acc = 0.f;
        for (int i = 0; i < deg; ++i) {
            float a = __shfl(exv, i);
            int si = __shfl(sv, i);
            acc = fmaf(emb[(long)si * DD + lane], a, acc);
        }
        Nh[(long)gw * DD + lane] = acc * inv;
    } else {
        float m = -3.4e38f;
        for (int i = lane; i < deg; i += 64) m = fmaxf(m, att[eidx[b + i]]);
#pragma unroll
        for (int off = 32; off; off >>= 1) m = fmaxf(m, __shfl_xor(m, off));
        float s = 0.f, acc = 0.f;
        for (int i = 0; i < deg; ++i) {
            unsigned e = eidx[b + i];
            float ex = expf(att[e] - m);
            s += ex;
            acc = fmaf(emb[(long)src[e] * DD + lane], ex, acc);
        }
        float inv = 1.f / s;
        for (int i = lane; i < deg; i += 64) {
            unsigned e = eidx[b + i];
            att[e] = expf(att[e] - m) * inv;
        }
        Nh[(long)gw * DD + lane] = acc * inv;
    }
}

// ---- Layer-1 aggregation: 32-lane group per dst, a[e] precomputed in att ----
__global__ void k_aggs1(const float* __restrict__ outb, const float* __restrict__ att,
                        const int* __restrict__ src,
                        const unsigned* __restrict__ cnt, const unsigned* __restrict__ basep,
                        const unsigned* __restrict__ eidx,
                        float* __restrict__ Nh1)
{
    int g = (int)(((long)blockIdx.x * blockDim.x + threadIdx.x) >> 5);
    int l5 = threadIdx.x & 31;
    if (g >= NN) return;
    int deg = (int)cnt[g];
    float acc = 0.f;
    if (deg > 0) {
        long b = basep[g];
        unsigned e = 0; float a = 0.f; int sv = 0;
        if (l5 < deg) {
            e = eidx[b + l5];
            a = att[e];
            sv = src[e];
        }
        int dmin = (deg < 32) ? deg : 32;
        for (int i = 0; i < dmin; ++i) {
            float ai = __shfl(a, i, 32);
            int si = __shfl(sv, i, 32);
            acc = fmaf(outb[(long)si * 112 + 64 + l5], ai, acc);
        }
        for (int i = 32; i < deg; ++i) {
            unsigned e2 = eidx[b + i];
            float a2 = att[e2];
            int s2 = src[e2];
            acc = fmaf(outb[(long)s2 * 112 + 64 + l5], a2, acc);
        }
    }
    Nh1[(long)g * 32 + l5] = acc;
}

// ---- Kernel E (v2): layer-0 node update with TRANSPOSED W in LDS ----
// Original lane-j gather W[j*64+dd] hit ~64 cache lines per load instruction
// (transaction-bound: 272us at 2.9% HBM / 23% VALU). W1T/W2T staged once per
// block, padded [64][33] -> conflict-free; lane j reads WT[dd][j] (1 LDS op).
#define NPB0 32
__global__ void __launch_bounds__(256)
k_node0t(const float* __restrict__ emb, const float* __restrict__ Nh,
         const float* __restrict__ W1, const float* __restrict__ b1,
         const float* __restrict__ W2, const float* __restrict__ b2,
         float* __restrict__ out)
{
    __shared__ float W1T[64][33];
    __shared__ float W2T[64][33];
    int t = threadIdx.x;
#pragma unroll
    for (int i = 0; i < 8; ++i) {
        int idx = i * 256 + t;          // 0..2047; row j=idx>>6, col dd=idx&63
        W1T[idx & 63][idx >> 6] = W1[idx];
        W2T[idx & 63][idx >> 6] = W2[idx];
    }
    __syncthreads();
    int wv = t >> 6, lane = t & 63, j = lane & 31;
    const float* __restrict__ WT = (lane < 32) ? &W1T[0][0] : &W2T[0][0];
    float bj = (lane < 32) ? b1[j] : b2[j];
    int n0 = blockIdx.x * NPB0;
    int n1 = (n0 + NPB0 < NN) ? n0 + NPB0 : NN;
    for (int node = n0 + wv; node < n1; node += 4) {
        const float* __restrict__ x  = emb + (long)node * DD;
        const float* __restrict__ nh = Nh + (long)node * DD;
        float acc = 0.f;
#pragma unroll 8
        for (int dd = 0; dd < DD; ++dd) {
            float xv = x[dd], nv = nh[dd];
            float v = (lane < 32) ? (xv + nv) : (xv * nv);
            acc = fmaf(v, WT[dd * 33 + j], acc);
        }
        acc += bj;
        acc = (acc >= 0.f) ? acc : 0.01f * acc;
        float other = __shfl_down(acc, 32);
        float h = acc + other;
        float ss = h * h;
#pragma unroll
        for (int off = 16; off; off >>= 1) ss += __shfl_xor(ss, off);
        float nrm = sqrtf(ss);
        float hn = h / fmaxf(nrm, 1e-12f);
        out[(long)node * 112 + lane] = x[lane];
        if (lane < 32) out[(long)node * 112 + 64 + j] = hn;
    }
}

// ---- Kernel G (v2): layer-1 node update with TRANSPOSED W in LDS ----
// BUGFIX vs round 10: W1_1/W2_1 have 512 elements but block=256 threads;
// the old `if (t < 512)` staged only the first 256 -> garbage in upper LDS
// rows -> absmax 0.65. Now a 2-iteration loop stages all 512.
#define NPB1 32
__global__ void __launch_bounds__(256)
k_node1t(const float* __restrict__ outbuf, const float* __restrict__ Nh1,
         const float* __restrict__ W1, const float* __restrict__ b1,
         const float* __restrict__ W2, const float* __restrict__ b2,
         float* __restrict__ out)
{
    __shared__ float W1T[32][17];
    __shared__ float W2T[32][17];
    int t = threadIdx.x;
#pragma unroll
    for (int i = 0; i < 2; ++i) {
        int idx = i * 256 + t;           // 0..511; row j=idx>>5, col dd=idx&31
        W1T[idx & 31][idx >> 5] = W1[idx];
        W2T[idx & 31][idx >> 5] = W2[idx];
    }
    __syncthreads();
    int grp = t >> 5;                    // 8 node-slots per block pass
    int l5 = t & 31, j = l5 & 15;
    const float* __restrict__ WT = (l5 < 16) ? &W1T[0][0] : &W2T[0][0];
    float bj = (l5 < 16) ? b1[j] : b2[j];
    int n0 = blockIdx.x * NPB1;
    int n1 = (n0 + NPB1 < NN) ? n0 + NPB1 : NN;
    for (int node = n0 + grp; node < n1; node += 8) {
        const float* __restrict__ x  = outbuf + (long)node * 112 + 64;
        const float* __restrict__ nh = Nh1 + (long)node * 32;
        float acc = 0.f;
#pragma unroll 8
        for (int dd = 0; dd < 32; ++dd) {
            float xv = x[dd], nv = nh[dd];
            float v = (l5 < 16) ? (xv + nv) : (xv * nv);
            acc = fmaf(v, WT[dd * 17 + j], acc);
        }
        acc += bj;
        acc = (acc >= 0.f) ? acc : 0.01f * acc;
        float other = __shfl_down(acc, 16, 32);
        float h = acc + other;
        float ss = h * h;
#pragma unroll
        for (int off = 8; off; off >>= 1) ss += __shfl_xor(ss, off);
        float nrm = sqrtf(ss);
        float hn = h / fmaxf(nrm, 1e-12f);
        if (l5 < 16) out[(long)node * 112 + 96 + j] = hn;
    }
}

// ================= fallback path (ws too small): round-1 kernels =================
__global__ void k_att(const float* __restrict__ emb, const float* __restrict__ rel,
                      const float* __restrict__ WR, const int* __restrict__ src,
                      const int* __restrict__ dst, const int* __restrict__ et,
                      float* __restrict__ att, unsigned* __restrict__ mkey)
{
    int e = (int)((blockIdx.x * blockDim.x + threadIdx.x) >> 6);
    int lane = threadIdx.x & 63;
    if (e >= NE) return;
    int s = src[e], d = dst[e], r = et[e];
    const float* __restrict__ es = emb + (long)s * DD;
    const float* __restrict__ eh = emb + (long)d * DD;
    const float* __restrict__ w  = WR + r * (DD * DDR) + lane;
    float at = 0.f, ah = 0.f;
#pragma unroll 8
    for (int dd = 0; dd < DD; ++dd) {
        float ws = w[dd * DDR];
        at = fmaf(es[dd], ws, at);
        ah = fmaf(eh[dd], ws, ah);
    }
    float term = at * tanhf(ah + rel[r * DDR + lane]);
#pragma unroll
    for (int off = 32; off; off >>= 1) term += __shfl_xor(term, off);
    if (lane == 0) {
        att[e] = term;
        atomicMax(mkey + d, enc_f(term));
    }
}

__global__ void k_expsum(const int* __restrict__ dst, float* __restrict__ att,
                         const unsigned* __restrict__ mkey, float* __restrict__ ssum)
{
    int e = blockIdx.x * blockDim.x + threadIdx.x;
    if (e >= NE) return;
    int d = dst[e];
    float ex = expf(att[e] - dec_f(mkey[d]));
    att[e] = ex;
    atomicAdd(ssum + d, ex);
}

__global__ void k_agg0(const float* __restrict__ emb, const int* __restrict__ src,
                       const int* __restrict__ dst, float* __restrict__ att,
                       const float* __restrict__ ssum, float* __restrict__ Nh)
{
    int e = (int)((blockIdx.x * blockDim.x + threadIdx.x) >> 6);
    int lane = threadIdx.x & 63;
    if (e >= NE) return;
    int s = src[e], d = dst[e];
    float a = att[e] / ssum[d];
    if (lane == 0) att[e] = a;
    float v = emb[(long)s * DD + lane] * a;
    atomicAdd(Nh + (long)d * DD + lane, v);
}

__global__ void k_agg1(const float* __restrict__ out, const int* __restrict__ src,
                       const int* __restrict__ dst, const float* __restrict__ att,
                       float* __restrict__ Nh1)
{
    int idx = blockIdx.x * blockDim.x + threadIdx.x;
    int e = idx >> 5;
    int j = idx & 31;
    if (e >= NE) return;
    int s = src[e], d = dst[e];
    float a = att[e];
    float v = out[(long)s * 112 + 64 + j] * a;
    atomicAdd(Nh1 + (long)d * 32 + j, v);
}

extern "C" void kernel_launch(void* const* d_in, const int* in_sizes, int n_in,
                              void* d_out, int out_size, void* d_ws, size_t ws_size,
                              hipStream_t stream) {
    const float* emb  = (const float*)d_in[0];
    const float* rel  = (const float*)d_in[1];
    const float* WR   = (const float*)d_in[2];
    const float* W1_0 = (const float*)d_in[3];
    const float* b1_0 = (const float*)d_in[4];
    const float* W2_0 = (const float*)d_in[5];
    const float* b2_0 = (const float*)d_in[6];
    const float* W1_1 = (const float*)d_in[7];
    const float* b1_1 = (const float*)d_in[8];
    const float* W2_1 = (const float*)d_in[9];
    const float* b2_1 = (const float*)d_in[10];
    const int*   src  = (const int*)d_in[11];
    const int*   dst  = (const int*)d_in[12];
    const int*   et   = (const int*)d_in[13];
    float* out = (float*)d_out;

    // main-path workspace (4B units):
    // [cnt NN][gcur 64][base NN][curs NN][Nh0 64NN][Nh1 32NN][att NE][eidx NE][proj bf16 NR*NN*64]
    unsigned* cnt   = (unsigned*)d_ws;
    unsigned* gcur  = cnt + NN;
    unsigned* basep = cnt + NN + 64;
    unsigned* curs  = cnt + 2 * NN + 64;
    float* Nh0  = (float*)d_ws + 3 * NN + 64;
    float* Nh1  = (float*)d_ws + (3 + DD) * NN + 64;
    float* att  = (float*)d_ws + (3 + DD + 32) * NN + 64;
    unsigned* eidx = (unsigned*)(att + NE);
    unsigned* proj = eidx + NE;

    size_t need = ((size_t)(3 + DD + 32) * NN + 64 + 2 * (size_t)NE) * 4
                + (size_t)NN * NR * DDR * 2;

    if (ws_size >= need) {
        hipMemsetAsync(d_ws, 0, (size_t)(NN + 64) * sizeof(unsigned), stream);  // cnt + gcur
        k_hist<<<dim3((NE + 255) / 256), dim3(256), 0, stream>>>(dst, cnt);
        k_projm<<<dim3((NN + 127) / 128, NR), dim3(256), 0, stream>>>(
            emb, WR, (unsigned short*)proj);
        k_attg<<<dim3((int)(((long)NE * 16 + 255) / 256)), dim3(256), 0, stream>>>(
            proj, rel, src, dst, et, att);
        k_base<<<dim3((NN + 255) / 256), dim3(256), 0, stream>>>(cnt, gcur, basep, curs);
        k_scatter<<<dim3((NE + 255) / 256), dim3(256), 0, stream>>>(dst, curs, eidx);
        k_fused0<<<dim3((int)(((long)NN * 64 + 255) / 256)), dim3(256), 0, stream>>>(
            emb, att, src, cnt, basep, eidx, Nh0);
        k_node0t<<<dim3((NN + NPB0 - 1) / NPB0), dim3(256), 0, stream>>>(
            emb, Nh0, W1_0, b1_0, W2_0, b2_0, out);
        k_aggs1<<<dim3((int)(((long)NN * 32 + 255) / 256)), dim3(256), 0, stream>>>(
            out, att, src, cnt, basep, eidx, Nh1);
        k_node1t<<<dim3((NN + NPB1 - 1) / NPB1), dim3(256), 0, stream>>>(
            out, Nh1, W1_1, b1_1, W2_1, b2_1, out);
    } else {
        // fallback: round-1 atomic pipeline, old layout
        unsigned* mkey = (unsigned*)d_ws;
        float* ssum = (float*)d_ws + NN;
        float* fNh0 = (float*)d_ws + 2 * NN;
        float* fNh1 = (float*)d_ws + (2 + DD) * NN;
        float* fatt = (float*)d_ws + (2 + DD + 32) * NN;
        hipMemsetAsync(d_ws, 0, (size_t)(2 + DD + 32) * NN * sizeof(float), stream);
        k_att<<<dim3((int)(((long)NE * 64 + 255) / 256)), dim3(256), 0, stream>>>(
            emb, rel, WR, src, dst, et, fatt, mkey);
        k_expsum<<<dim3((NE + 255) / 256), dim3(256), 0, stream>>>(dst, fatt, mkey, ssum);
        k_agg0<<<dim3((int)(((long)NE * 64 + 255) / 256)), dim3(256), 0, stream>>>(
            emb, src, dst, fatt, ssum, fNh0);
        k_node0t<<<dim3((NN + NPB0 - 1) / NPB0), dim3(256), 0, stream>>>(
            emb, fNh0, W1_0, b1_0, W2_0, b2_0, out);
        k_agg1<<<dim3((int)(((long)NE * 32 + 255) / 256)), dim3(256), 0, stream>>>(
            out, src, dst, fatt, fNh1);
        k_node1t<<<dim3((NN + NPB1 - 1) / NPB1), dim3(256), 0, stream>>>(
            out, fNh1, W1_1, b1_1, W2_1, b2_1, out);
    }
}

// Round 12
// 645.895 us; speedup vs baseline: 2.4932x; 1.1467x over previous
//
#include <hip/hip_runtime.h>
#include <hip/hip_bf16.h>
#include <math.h>

#define NN 100000
#define NE 1600000
#define NR 8
#define DD 64
#define DDR 64

typedef __attribute__((ext_vector_type(8))) short bf8v;   // 8 x bf16 (4 VGPRs)
typedef __attribute__((ext_vector_type(4))) float f4v;    // MFMA accumulator

// ---- order-preserving float<->uint encoding (fallback path only) ----
__device__ __forceinline__ unsigned enc_f(float f) {
    unsigned u = __float_as_uint(f);
    return (u & 0x80000000u) ? ~u : (u | 0x80000000u);
}
__device__ __forceinline__ float dec_f(unsigned u) {
    return (u & 0x80000000u) ? __uint_as_float(u & 0x7FFFFFFFu) : __uint_as_float(~u);
}

__device__ __forceinline__ float bflo(unsigned u) { return __uint_as_float(u << 16); }
__device__ __forceinline__ float bfhi(unsigned u) { return __uint_as_float(u & 0xFFFF0000u); }
__device__ __forceinline__ short f2bfs(float x) {
    __hip_bfloat16 h = __float2bfloat16(x);
    return *reinterpret_cast<short*>(&h);
}

// ---- Kernel PM: proj[r][n][c] = emb[n] @ W_R[r] via MFMA ----
__global__ void __launch_bounds__(256)
k_projm(const float* __restrict__ emb, const float* __restrict__ WR,
        unsigned short* __restrict__ proj)
{
    int t = threadIdx.x;
    int wv = t >> 6, l = t & 63;
    int lo = l & 15, hi = l >> 4;
    int r = blockIdx.y;
    int colbase = (wv & 1) * 32;
    int nwbase = blockIdx.x * 128 + (wv >> 1) * 64;

    const float* __restrict__ wb = WR + (long)r * (DD * DDR) + (hi * 8) * DDR + colbase + lo;
    bf8v B00, B01, B10, B11;
#pragma unroll
    for (int j = 0; j < 8; ++j) {
        B00[j] = f2bfs(wb[(0 * 32 + j) * DDR + 0]);
        B01[j] = f2bfs(wb[(1 * 32 + j) * DDR + 0]);
        B10[j] = f2bfs(wb[(0 * 32 + j) * DDR + 16]);
        B11[j] = f2bfs(wb[(1 * 32 + j) * DDR + 16]);
    }

    for (int nt = 0; nt < 4; ++nt) {
        int nb = nwbase + nt * 16;
        int arow = nb + lo;
        float4 xa0 = make_float4(0.f, 0.f, 0.f, 0.f), xa1 = xa0, xb0 = xa0, xb1 = xa0;
        if (arow < NN) {
            const float* __restrict__ xr = emb + (long)arow * DD + hi * 8;
            xa0 = *(const float4*)(xr);
            xa1 = *(const float4*)(xr + 4);
            xb0 = *(const float4*)(xr + 32);
            xb1 = *(const float4*)(xr + 36);
        }
        bf8v A0, A1;
        A0[0] = f2bfs(xa0.x); A0[1] = f2bfs(xa0.y); A0[2] = f2bfs(xa0.z); A0[3] = f2bfs(xa0.w);
        A0[4] = f2bfs(xa1.x); A0[5] = f2bfs(xa1.y); A0[6] = f2bfs(xa1.z); A0[7] = f2bfs(xa1.w);
        A1[0] = f2bfs(xb0.x); A1[1] = f2bfs(xb0.y); A1[2] = f2bfs(xb0.z); A1[3] = f2bfs(xb0.w);
        A1[4] = f2bfs(xb1.x); A1[5] = f2bfs(xb1.y); A1[6] = f2bfs(xb1.z); A1[7] = f2bfs(xb1.w);

        f4v acc0 = {0.f, 0.f, 0.f, 0.f}, acc1 = {0.f, 0.f, 0.f, 0.f};
        acc0 = __builtin_amdgcn_mfma_f32_16x16x32_bf16(A0, B00, acc0, 0, 0, 0);
        acc0 = __builtin_amdgcn_mfma_f32_16x16x32_bf16(A1, B01, acc0, 0, 0, 0);
        acc1 = __builtin_amdgcn_mfma_f32_16x16x32_bf16(A0, B10, acc1, 0, 0, 0);
        acc1 = __builtin_amdgcn_mfma_f32_16x16x32_bf16(A1, B11, acc1, 0, 0, 0);

#pragma unroll
        for (int i = 0; i < 4; ++i) {
            int rr = nb + hi * 4 + i;
            if (rr < NN) {
                long obase = ((long)r * NN + rr) * DDR + colbase + lo;
                proj[obase]      = (unsigned short)f2bfs(acc0[i]);
                proj[obase + 16] = (unsigned short)f2bfs(acc1[i]);
            }
        }
    }
}

// ---- CSR build ----
__global__ void k_hist(const int* __restrict__ dst, unsigned* __restrict__ cnt)
{
    int e = blockIdx.x * blockDim.x + threadIdx.x;
    if (e >= NE) return;
    atomicAdd(cnt + dst[e], 1u);
}

__global__ void k_base(const unsigned* __restrict__ cnt, unsigned* __restrict__ gcur,
                       unsigned* __restrict__ base, unsigned* __restrict__ curs)
{
    int i = blockIdx.x * blockDim.x + threadIdx.x;
    int lane = threadIdx.x & 63;
    unsigned v = (i < NN) ? cnt[i] : 0u;
    unsigned p = v;
#pragma unroll
    for (int off = 1; off < 64; off <<= 1) {
        unsigned q = __shfl_up(p, off);
        if (lane >= off) p += q;
    }
    unsigned tot = __shfl(p, 63);
    unsigned gb = 0;
    if (lane == 0) gb = atomicAdd(gcur, tot);
    gb = __shfl(gb, 0);
    if (i < NN) {
        unsigned b = gb + p - v;
        base[i] = b;
        curs[i] = b;
    }
}

// Scatter PAYLOAD (src | etype<<28) in CSR order — downstream kernels never
// re-gather src/et/eidx, and softmax weights store contiguously (acsr).
__global__ void k_scatter2(const int* __restrict__ dst, const int* __restrict__ src,
                           const int* __restrict__ et, unsigned* __restrict__ curs,
                           unsigned* __restrict__ srcet)
{
    int e = blockIdx.x * blockDim.x + threadIdx.x;
    if (e >= NE) return;
    unsigned pos = atomicAdd(curs + dst[e], 1u);
    srcet[pos] = (unsigned)src[e] | ((unsigned)et[e] << 28);
}

// ---- MEGA0: attention logits + edge softmax + layer-0 aggregation + layer-0
// MLP, one wave per dst node. Writes ego (cols 0..64) + h1 (cols 64..96) and
// normalized weights acsr[b..b+deg) for layer 1.
__global__ void __launch_bounds__(256)
k_mega0(const float* __restrict__ emb, const unsigned short* __restrict__ proj,
        const float* __restrict__ rel,
        const unsigned* __restrict__ cnt, const unsigned* __restrict__ basep,
        const unsigned* __restrict__ srcet, float* __restrict__ acsr,
        const float* __restrict__ W1, const float* __restrict__ b1,
        const float* __restrict__ W2, const float* __restrict__ b2,
        float* __restrict__ out)
{
    __shared__ float W1T[64][33];
    __shared__ float W2T[64][33];
    __shared__ float sm1[4][64];
    __shared__ float sm2[4][64];
    int t = threadIdx.x;
#pragma unroll
    for (int i = 0; i < 8; ++i) {
        int idx = i * 256 + t;          // j=idx>>6, dd=idx&63
        W1T[idx & 63][idx >> 6] = W1[idx];
        W2T[idx & 63][idx >> 6] = W2[idx];
    }
    int wv = t >> 6, lane = t & 63;
    int g = blockIdx.x * 4 + wv;        // NN % 4 == 0: always valid
    int deg = (int)cnt[g];
    long b = basep[g];
    float Nh = 0.f;
    if (deg > 0 && deg <= 64) {
        unsigned se = 0;
        if (lane < deg) se = srcet[b + lane];       // coalesced CSR read
        float attv = -3.4e38f, m = -3.4e38f;
        for (int i = 0; i < deg; ++i) {
            unsigned sei = __shfl(se, i);
            int s = (int)(sei & 0x0FFFFFFFu);
            int r = (int)(sei >> 28);
            float pv = __uint_as_float(((unsigned)proj[((long)r * NN + s) * DDR + lane]) << 16);
            float dv = __uint_as_float(((unsigned)proj[((long)r * NN + g) * DDR + lane]) << 16);
            float rv = rel[r * DDR + lane];
            float term = pv * tanhf(dv + rv);
#pragma unroll
            for (int off = 32; off; off >>= 1) term += __shfl_xor(term, off);
            if (lane == i) attv = term;             // term is wave-uniform
            m = fmaxf(m, term);
        }
        float exv = (lane < deg) ? expf(attv - m) : 0.f;
        float s_ = exv;
#pragma unroll
        for (int off = 32; off; off >>= 1) s_ += __shfl_xor(s_, off);
        float inv = 1.f / s_;
        if (lane < deg) acsr[b + lane] = exv * inv; // contiguous write
        float acc = 0.f;
        for (int i = 0; i < deg; ++i) {
            float a = __shfl(exv, i);
            int s = (int)(__shfl(se, i) & 0x0FFFFFFFu);
            acc = fmaf(emb[(long)s * DD + lane], a, acc);
        }
        Nh = acc * inv;
    } else if (deg > 64) {
        // slow path (deg>64 not expected for Poisson(16) but kept correct)
        float m = -3.4e38f;
        for (int i = 0; i < deg; ++i) {
            unsigned sei = srcet[b + i];
            int s = (int)(sei & 0x0FFFFFFFu);
            int r = (int)(sei >> 28);
            float pv = __uint_as_float(((unsigned)proj[((long)r * NN + s) * DDR + lane]) << 16);
            float dv = __uint_as_float(((unsigned)proj[((long)r * NN + g) * DDR + lane]) << 16);
            float rv = rel[r * DDR + lane];
            float term = pv * tanhf(dv + rv);
#pragma unroll
            for (int off = 32; off; off >>= 1) term += __shfl_xor(term, off);
            if (lane == 0) acsr[b + i] = term;      // raw logits
            m = fmaxf(m, term);
        }
        float s_ = 0.f;
        for (int i = lane; i < deg; i += 64) s_ += expf(acsr[b + i] - m);
#pragma unroll
        for (int off = 32; off; off >>= 1) s_ += __shfl_xor(s_, off);
        float inv = 1.f / s_;
        float acc = 0.f;
        for (int i = 0; i < deg; ++i) {
            float raw = acsr[b + i];                // read-before-overwrite
            float a = expf(raw - m) * inv;
            int s = (int)(srcet[b + i] & 0x0FFFFFFFu);
            acc = fmaf(emb[(long)s * DD + lane], a, acc);
            if (lane == 0) acsr[b + i] = a;
        }
        Nh = acc;
    }
    float x = emb[(long)g * DD + lane];
    sm1[wv][lane] = x + Nh;
    sm2[wv][lane] = x * Nh;
    __syncthreads();
    int j = lane & 31;
    const float* __restrict__ WT = (lane < 32) ? &W1T[0][0] : &W2T[0][0];
    const float* __restrict__ sm = (lane < 32) ? &sm1[wv][0] : &sm2[wv][0];
    float accm = (lane < 32) ? b1[j] : b2[j];
#pragma unroll 8
    for (int dd = 0; dd < 64; ++dd)
        accm = fmaf(sm[dd], WT[dd * 33 + j], accm);
    accm = (accm >= 0.f) ? accm : 0.01f * accm;
    float other = __shfl_down(accm, 32);
    float h = accm + other;
    float ss = h * h;
#pragma unroll
    for (int off = 16; off; off >>= 1) ss += __shfl_xor(ss, off);
    float hn = h / fmaxf(sqrtf(ss), 1e-12f);
    out[(long)g * 112 + lane] = x;
    if (lane < 32) out[(long)g * 112 + 64 + j] = hn;
}

// ---- MEGA1: layer-1 aggregation + layer-1 MLP, 32-lane group per dst ----
__global__ void __launch_bounds__(256)
k_mega1(const float* __restrict__ acsr, const unsigned* __restrict__ srcet,
        const unsigned* __restrict__ cnt, const unsigned* __restrict__ basep,
        const float* __restrict__ W1, const float* __restrict__ b1,
        const float* __restrict__ W2, const float* __restrict__ b2,
        float* __restrict__ out)
{
    __shared__ float W1T[32][17];
    __shared__ float W2T[32][17];
    __shared__ float sm1[8][32];
    __shared__ float sm2[8][32];
    int t = threadIdx.x;
#pragma unroll
    for (int i = 0; i < 2; ++i) {
        int idx = i * 256 + t;          // j=idx>>5, dd=idx&31
        W1T[idx & 31][idx >> 5] = W1[idx];
        W2T[idx & 31][idx >> 5] = W2[idx];
    }
    int grp = t >> 5, l5 = t & 31;
    int g = blockIdx.x * 8 + grp;       // NN % 8 == 0: always valid
    int deg = (int)cnt[g];
    float acc = 0.f;
    if (deg > 0) {
        long b = basep[g];
        unsigned se = 0; float a = 0.f;
        if (l5 < deg) { se = srcet[b + l5]; a = acsr[b + l5]; }
        int dmin = (deg < 32) ? deg : 32;
        for (int i = 0; i < dmin; ++i) {
            float ai = __shfl(a, i, 32);
            int si = (int)(__shfl(se, i, 32) & 0x0FFFFFFFu);
            acc = fmaf(out[(long)si * 112 + 64 + l5], ai, acc);
        }
        for (int i = 32; i < deg; ++i) {
            float ai = acsr[b + i];
            int si = (int)(srcet[b + i] & 0x0FFFFFFFu);
            acc = fmaf(out[(long)si * 112 + 64 + l5], ai, acc);
        }
    }
    float x = out[(long)g * 112 + 64 + l5];
    sm1[grp][l5] = x + acc;
    sm2[grp][l5] = x * acc;
    __syncthreads();
    int j = l5 & 15;
    const float* __restrict__ WT = (l5 < 16) ? &W1T[0][0] : &W2T[0][0];
    const float* __restrict__ sm = (l5 < 16) ? &sm1[grp][0] : &sm2[grp][0];
    float accm = (l5 < 16) ? b1[j] : b2[j];
#pragma unroll 8
    for (int dd = 0; dd < 32; ++dd)
        accm = fmaf(sm[dd], WT[dd * 17 + j], accm);
    accm = (accm >= 0.f) ? accm : 0.01f * accm;
    float other = __shfl_down(accm, 16, 32);
    float h = accm + other;
    float ss = h * h;
#pragma unroll
    for (int off = 8; off; off >>= 1) ss += __shfl_xor(ss, off);
    float hn = h / fmaxf(sqrtf(ss), 1e-12f);
    if (l5 < 16) out[(long)g * 112 + 96 + j] = hn;
}

// ================= fallback path (ws too small): round-1 kernels =================
__global__ void k_att(const float* __restrict__ emb, const float* __restrict__ rel,
                      const float* __restrict__ WR, const int* __restrict__ src,
                      const int* __restrict__ dst, const int* __restrict__ et,
                      float* __restrict__ att, unsigned* __restrict__ mkey)
{
    int e = (int)((blockIdx.x * blockDim.x + threadIdx.x) >> 6);
    int lane = threadIdx.x & 63;
    if (e >= NE) return;
    int s = src[e], d = dst[e], r = et[e];
    const float* __restrict__ es = emb + (long)s * DD;
    const float* __restrict__ eh = emb + (long)d * DD;
    const float* __restrict__ w  = WR + r * (DD * DDR) + lane;
    float at = 0.f, ah = 0.f;
#pragma unroll 8
    for (int dd = 0; dd < DD; ++dd) {
        float ws = w[dd * DDR];
        at = fmaf(es[dd], ws, at);
        ah = fmaf(eh[dd], ws, ah);
    }
    float term = at * tanhf(ah + rel[r * DDR + lane]);
#pragma unroll
    for (int off = 32; off; off >>= 1) term += __shfl_xor(term, off);
    if (lane == 0) {
        att[e] = term;
        atomicMax(mkey + d, enc_f(term));
    }
}

__global__ void k_expsum(const int* __restrict__ dst, float* __restrict__ att,
                         const unsigned* __restrict__ mkey, float* __restrict__ ssum)
{
    int e = blockIdx.x * blockDim.x + threadIdx.x;
    if (e >= NE) return;
    int d = dst[e];
    float ex = expf(att[e] - dec_f(mkey[d]));
    att[e] = ex;
    atomicAdd(ssum + d, ex);
}

__global__ void k_agg0(const float* __restrict__ emb, const int* __restrict__ src,
                       const int* __restrict__ dst, float* __restrict__ att,
                       const float* __restrict__ ssum, float* __restrict__ Nh)
{
    int e = (int)((blockIdx.x * blockDim.x + threadIdx.x) >> 6);
    int lane = threadIdx.x & 63;
    if (e >= NE) return;
    int s = src[e], d = dst[e];
    float a = att[e] / ssum[d];
    if (lane == 0) att[e] = a;
    float v = emb[(long)s * DD + lane] * a;
    atomicAdd(Nh + (long)d * DD + lane, v);
}

__global__ void k_agg1(const float* __restrict__ out, const int* __restrict__ src,
                       const int* __restrict__ dst, const float* __restrict__ att,
                       float* __restrict__ Nh1)
{
    int idx = blockIdx.x * blockDim.x + threadIdx.x;
    int e = idx >> 5;
    int j = idx & 31;
    if (e >= NE) return;
    int s = src[e], d = dst[e];
    float a = att[e];
    float v = out[(long)s * 112 + 64 + j] * a;
    atomicAdd(Nh1 + (long)d * 32 + j, v);
}

#define NPB0 32
__global__ void __launch_bounds__(256)
k_node0t(const float* __restrict__ emb, const float* __restrict__ Nh,
         const float* __restrict__ W1, const float* __restrict__ b1,
         const float* __restrict__ W2, const float* __restrict__ b2,
         float* __restrict__ out)
{
    __shared__ float W1T[64][33];
    __shared__ float W2T[64][33];
    int t = threadIdx.x;
#pragma unroll
    for (int i = 0; i < 8; ++i) {
        int idx = i * 256 + t;
        W1T[idx & 63][idx >> 6] = W1[idx];
        W2T[idx & 63][idx >> 6] = W2[idx];
    }
    __syncthreads();
    int wv = t >> 6, lane = t & 63, j = lane & 31;
    const float* __restrict__ WT = (lane < 32) ? &W1T[0][0] : &W2T[0][0];
    float bj = (lane < 32) ? b1[j] : b2[j];
    int n0 = blockIdx.x * NPB0;
    int n1 = (n0 + NPB0 < NN) ? n0 + NPB0 : NN;
    for (int node = n0 + wv; node < n1; node += 4) {
        const float* __restrict__ x  = emb + (long)node * DD;
        const float* __restrict__ nh = Nh + (long)node * DD;
        float acc = 0.f;
#pragma unroll 8
        for (int dd = 0; dd < DD; ++dd) {
            float xv = x[dd], nv = nh[dd];
            float v = (lane < 32) ? (xv + nv) : (xv * nv);
            acc = fmaf(v, WT[dd * 33 + j], acc);
        }
        acc += bj;
        acc = (acc >= 0.f) ? acc : 0.01f * acc;
        float other = __shfl_down(acc, 32);
        float h = acc + other;
        float ss = h * h;
#pragma unroll
        for (int off = 16; off; off >>= 1) ss += __shfl_xor(ss, off);
        float hn = h / fmaxf(sqrtf(ss), 1e-12f);
        out[(long)node * 112 + lane] = x[lane];
        if (lane < 32) out[(long)node * 112 + 64 + j] = hn;
    }
}

#define NPB1 32
__global__ void __launch_bounds__(256)
k_node1t(const float* __restrict__ outbuf, const float* __restrict__ Nh1,
         const float* __restrict__ W1, const float* __restrict__ b1,
         const float* __restrict__ W2, const float* __restrict__ b2,
         float* __restrict__ out)
{
    __shared__ float W1T[32][17];
    __shared__ float W2T[32][17];
    int t = threadIdx.x;
#pragma unroll
    for (int i = 0; i < 2; ++i) {
        int idx = i * 256 + t;
        W1T[idx & 31][idx >> 5] = W1[idx];
        W2T[idx & 31][idx >> 5] = W2[idx];
    }
    __syncthreads();
    int grp = t >> 5;
    int l5 = t & 31, j = l5 & 15;
    const float* __restrict__ WT = (l5 < 16) ? &W1T[0][0] : &W2T[0][0];
    float bj = (l5 < 16) ? b1[j] : b2[j];
    int n0 = blockIdx.x * NPB1;
    int n1 = (n0 + NPB1 < NN) ? n0 + NPB1 : NN;
    for (int node = n0 + grp; node < n1; node += 8) {
        const float* __restrict__ x  = outbuf + (long)node * 112 + 64;
        const float* __restrict__ nh = Nh1 + (long)node * 32;
        float acc = 0.f;
#pragma unroll 8
        for (int dd = 0; dd < 32; ++dd) {
            float xv = x[dd], nv = nh[dd];
            float v = (l5 < 16) ? (xv + nv) : (xv * nv);
            acc = fmaf(v, WT[dd * 17 + j], acc);
        }
        acc += bj;
        acc = (acc >= 0.f) ? acc : 0.01f * acc;
        float other = __shfl_down(acc, 16, 32);
        float h = acc + other;
        float ss = h * h;
#pragma unroll
        for (int off = 8; off; off >>= 1) ss += __shfl_xor(ss, off);
        float hn = h / fmaxf(sqrtf(ss), 1e-12f);
        if (l5 < 16) out[(long)node * 112 + 96 + j] = hn;
    }
}

extern "C" void kernel_launch(void* const* d_in, const int* in_sizes, int n_in,
                              void* d_out, int out_size, void* d_ws, size_t ws_size,
                              hipStream_t stream) {
    const float* emb  = (const float*)d_in[0];
    const float* rel  = (const float*)d_in[1];
    const float* WR   = (const float*)d_in[2];
    const float* W1_0 = (const float*)d_in[3];
    const float* b1_0 = (const float*)d_in[4];
    const float* W2_0 = (const float*)d_in[5];
    const float* b2_0 = (const float*)d_in[6];
    const float* W1_1 = (const float*)d_in[7];
    const float* b1_1 = (const float*)d_in[8];
    const float* W2_1 = (const float*)d_in[9];
    const float* b2_1 = (const float*)d_in[10];
    const int*   src  = (const int*)d_in[11];
    const int*   dst  = (const int*)d_in[12];
    const int*   et   = (const int*)d_in[13];
    float* out = (float*)d_out;

    // main-path workspace (4B units):
    // [cnt NN][gcur 64][base NN][curs NN][acsr NE][srcet NE][proj bf16 NR*NN*64]
    unsigned* cnt   = (unsigned*)d_ws;
    unsigned* gcur  = cnt + NN;
    unsigned* basep = cnt + NN + 64;
    unsigned* curs  = cnt + 2 * NN + 64;
    float* acsr  = (float*)d_ws + 3 * NN + 64;
    unsigned* srcet = (unsigned*)(acsr + NE);
    unsigned* proj = srcet + NE;

    size_t need = ((size_t)3 * NN + 64 + 2 * (size_t)NE) * 4
                + (size_t)NN * NR * DDR * 2;

    if (ws_size >= need) {
        hipMemsetAsync(d_ws, 0, (size_t)(NN + 64) * sizeof(unsigned), stream);  // cnt + gcur
        k_hist<<<dim3((NE + 255) / 256), dim3(256), 0, stream>>>(dst, cnt);
        k_projm<<<dim3((NN + 127) / 128, NR), dim3(256), 0, stream>>>(
            emb, WR, (unsigned short*)proj);
        k_base<<<dim3((NN + 255) / 256), dim3(256), 0, stream>>>(cnt, gcur, basep, curs);
        k_scatter2<<<dim3((NE + 255) / 256), dim3(256), 0, stream>>>(
            dst, src, et, curs, srcet);
        k_mega0<<<dim3((NN + 3) / 4), dim3(256), 0, stream>>>(
            emb, (const unsigned short*)proj, rel, cnt, basep, srcet, acsr,
            W1_0, b1_0, W2_0, b2_0, out);
        k_mega1<<<dim3((NN + 7) / 8), dim3(256), 0, stream>>>(
            acsr, srcet, cnt, basep, W1_1, b1_1, W2_1, b2_1, out);
    } else {
        // fallback: round-1 atomic pipeline, old layout
        unsigned* mkey = (unsigned*)d_ws;
        float* ssum = (float*)d_ws + NN;
        float* fNh0 = (float*)d_ws + 2 * NN;
        float* fNh1 = (float*)d_ws + (2 + DD) * NN;
        float* fatt = (float*)d_ws + (2 + DD + 32) * NN;
        hipMemsetAsync(d_ws, 0, (size_t)(2 + DD + 32) * NN * sizeof(float), stream);
        k_att<<<dim3((int)(((long)NE * 64 + 255) / 256)), dim3(256), 0, stream>>>(
            emb, rel, WR, src, dst, et, fatt, mkey);
        k_expsum<<<dim3((NE + 255) / 256), dim3(256), 0, stream>>>(dst, fatt, mkey, ssum);
        k_agg0<<<dim3((int)(((long)NE * 64 + 255) / 256)), dim3(256), 0, stream>>>(
            emb, src, dst, fatt, ssum, fNh0);
        k_node0t<<<dim3((NN + NPB0 - 1) / NPB0), dim3(256), 0, stream>>>(
            emb, fNh0, W1_0, b1_0, W2_0, b2_0, out);
        k_agg1<<<dim3((int)(((long)NE * 32 + 255) / 256)), dim3(256), 0, stream>>>(
            out, src, dst, fatt, fNh1);
        k_node1t<<<dim3((NN + NPB1 - 1) / NPB1), dim3(256), 0, stream>>>(
            out, fNh1, W1_1, b1_1, W2_1, b2_1, out);
    }
}

// Round 13
// 491.498 us; speedup vs baseline: 3.2763x; 1.3141x over previous
//
#include <hip/hip_runtime.h>
#include <hip/hip_bf16.h>
#include <math.h>

#define NN 100000
#define NE 1600000
#define NR 8
#define DD 64
#define DDR 64

typedef __attribute__((ext_vector_type(8))) short bf8v;   // 8 x bf16 (4 VGPRs)
typedef __attribute__((ext_vector_type(4))) float f4v;    // MFMA accumulator

// ---- order-preserving float<->uint encoding (fallback path only) ----
__device__ __forceinline__ unsigned enc_f(float f) {
    unsigned u = __float_as_uint(f);
    return (u & 0x80000000u) ? ~u : (u | 0x80000000u);
}
__device__ __forceinline__ float dec_f(unsigned u) {
    return (u & 0x80000000u) ? __uint_as_float(u & 0x7FFFFFFFu) : __uint_as_float(~u);
}

__device__ __forceinline__ float bflo(unsigned u) { return __uint_as_float(u << 16); }
__device__ __forceinline__ float bfhi(unsigned u) { return __uint_as_float(u & 0xFFFF0000u); }
__device__ __forceinline__ short f2bfs(float x) {
    __hip_bfloat16 h = __float2bfloat16(x);
    return *reinterpret_cast<short*>(&h);
}

// fast tanh: (e-1)/(e+1), e = exp(2x). ~8 VALU ops vs ~25 for __ocml_tanh.
// |error| ~1e-6, negligible vs bf16-proj error budget. Clamp avoids inf/inf.
__device__ __forceinline__ float tanh_fast(float x) {
    x = fminf(fmaxf(x, -15.f), 15.f);
    float e = __expf(2.f * x);
    return (e - 1.f) * __builtin_amdgcn_rcpf(e + 1.f);
}

// ---- Kernel PM: proj[r][n][c] = emb[n] @ W_R[r] via MFMA ----
__global__ void __launch_bounds__(256)
k_projm(const float* __restrict__ emb, const float* __restrict__ WR,
        unsigned short* __restrict__ proj)
{
    int t = threadIdx.x;
    int wv = t >> 6, l = t & 63;
    int lo = l & 15, hi = l >> 4;
    int r = blockIdx.y;
    int colbase = (wv & 1) * 32;
    int nwbase = blockIdx.x * 128 + (wv >> 1) * 64;

    const float* __restrict__ wb = WR + (long)r * (DD * DDR) + (hi * 8) * DDR + colbase + lo;
    bf8v B00, B01, B10, B11;
#pragma unroll
    for (int j = 0; j < 8; ++j) {
        B00[j] = f2bfs(wb[(0 * 32 + j) * DDR + 0]);
        B01[j] = f2bfs(wb[(1 * 32 + j) * DDR + 0]);
        B10[j] = f2bfs(wb[(0 * 32 + j) * DDR + 16]);
        B11[j] = f2bfs(wb[(1 * 32 + j) * DDR + 16]);
    }

    for (int nt = 0; nt < 4; ++nt) {
        int nb = nwbase + nt * 16;
        int arow = nb + lo;
        float4 xa0 = make_float4(0.f, 0.f, 0.f, 0.f), xa1 = xa0, xb0 = xa0, xb1 = xa0;
        if (arow < NN) {
            const float* __restrict__ xr = emb + (long)arow * DD + hi * 8;
            xa0 = *(const float4*)(xr);
            xa1 = *(const float4*)(xr + 4);
            xb0 = *(const float4*)(xr + 32);
            xb1 = *(const float4*)(xr + 36);
        }
        bf8v A0, A1;
        A0[0] = f2bfs(xa0.x); A0[1] = f2bfs(xa0.y); A0[2] = f2bfs(xa0.z); A0[3] = f2bfs(xa0.w);
        A0[4] = f2bfs(xa1.x); A0[5] = f2bfs(xa1.y); A0[6] = f2bfs(xa1.z); A0[7] = f2bfs(xa1.w);
        A1[0] = f2bfs(xb0.x); A1[1] = f2bfs(xb0.y); A1[2] = f2bfs(xb0.z); A1[3] = f2bfs(xb0.w);
        A1[4] = f2bfs(xb1.x); A1[5] = f2bfs(xb1.y); A1[6] = f2bfs(xb1.z); A1[7] = f2bfs(xb1.w);

        f4v acc0 = {0.f, 0.f, 0.f, 0.f}, acc1 = {0.f, 0.f, 0.f, 0.f};
        acc0 = __builtin_amdgcn_mfma_f32_16x16x32_bf16(A0, B00, acc0, 0, 0, 0);
        acc0 = __builtin_amdgcn_mfma_f32_16x16x32_bf16(A1, B01, acc0, 0, 0, 0);
        acc1 = __builtin_amdgcn_mfma_f32_16x16x32_bf16(A0, B10, acc1, 0, 0, 0);
        acc1 = __builtin_amdgcn_mfma_f32_16x16x32_bf16(A1, B11, acc1, 0, 0, 0);

#pragma unroll
        for (int i = 0; i < 4; ++i) {
            int rr = nb + hi * 4 + i;
            if (rr < NN) {
                long obase = ((long)r * NN + rr) * DDR + colbase + lo;
                proj[obase]      = (unsigned short)f2bfs(acc0[i]);
                proj[obase + 16] = (unsigned short)f2bfs(acc1[i]);
            }
        }
    }
}

// ---- CSR build ----
__global__ void k_hist(const int* __restrict__ dst, unsigned* __restrict__ cnt)
{
    int e = blockIdx.x * blockDim.x + threadIdx.x;
    if (e >= NE) return;
    atomicAdd(cnt + dst[e], 1u);
}

__global__ void k_base(const unsigned* __restrict__ cnt, unsigned* __restrict__ gcur,
                       unsigned* __restrict__ base, unsigned* __restrict__ curs)
{
    int i = blockIdx.x * blockDim.x + threadIdx.x;
    int lane = threadIdx.x & 63;
    unsigned v = (i < NN) ? cnt[i] : 0u;
    unsigned p = v;
#pragma unroll
    for (int off = 1; off < 64; off <<= 1) {
        unsigned q = __shfl_up(p, off);
        if (lane >= off) p += q;
    }
    unsigned tot = __shfl(p, 63);
    unsigned gb = 0;
    if (lane == 0) gb = atomicAdd(gcur, tot);
    gb = __shfl(gb, 0);
    if (i < NN) {
        unsigned b = gb + p - v;
        base[i] = b;
        curs[i] = b;
    }
}

__global__ void k_scatter2(const int* __restrict__ dst, const int* __restrict__ src,
                           const int* __restrict__ et, unsigned* __restrict__ curs,
                           unsigned* __restrict__ srcet)
{
    int e = blockIdx.x * blockDim.x + threadIdx.x;
    if (e >= NE) return;
    unsigned pos = atomicAdd(curs + dst[e], 1u);
    srcet[pos] = (unsigned)src[e] | ((unsigned)et[e] << 28);
}

// ---- MEGA0: att logits (4 edges/wave-iter) + softmax + agg + layer-0 MLP ----
__global__ void __launch_bounds__(256)
k_mega0(const float* __restrict__ emb, const unsigned* __restrict__ proj,
        const float* __restrict__ rel,
        const unsigned* __restrict__ cnt, const unsigned* __restrict__ basep,
        const unsigned* __restrict__ srcet, float* __restrict__ acsr,
        const float* __restrict__ W1, const float* __restrict__ b1,
        const float* __restrict__ W2, const float* __restrict__ b2,
        float* __restrict__ out)
{
    __shared__ float W1T[64][33];
    __shared__ float W2T[64][33];
    __shared__ float sm1[4][64];
    __shared__ float sm2[4][64];
    __shared__ float att_s[4][64];
    int t = threadIdx.x;
#pragma unroll
    for (int i = 0; i < 8; ++i) {
        int idx = i * 256 + t;          // j=idx>>6, dd=idx&63
        W1T[idx & 63][idx >> 6] = W1[idx];
        W2T[idx & 63][idx >> 6] = W2[idx];
    }
    int wv = t >> 6, lane = t & 63;
    int g = blockIdx.x * 4 + wv;        // NN % 4 == 0: always valid
    int deg = (int)cnt[g];
    long b = basep[g];
    float Nh = 0.f;
    if (deg > 0 && deg <= 64) {
        unsigned se = 0;
        if (lane < deg) se = srcet[b + lane];       // coalesced CSR read
        // --- attention logits: 4 edges per iteration, 16 lanes each ---
        int gi = lane >> 4;             // edge sub-slot 0..3
        int lj = lane & 15;             // lane within edge group
        for (int k0 = 0; k0 < deg; k0 += 4) {
            int ei = k0 + gi;
            unsigned sei = __shfl(se, ei);          // garbage-safe (se=0 pad)
            int s = (int)(sei & 0x0FFFFFFFu);
            int r = (int)(sei >> 28);
            uint2 tv = *(const uint2*)(proj + ((long)r * NN + s) * 32 + lj * 2);
            uint2 hv = *(const uint2*)(proj + ((long)r * NN + g) * 32 + lj * 2);
            float4 rv = *(const float4*)(rel + r * DDR + lj * 4);
            float sum = bflo(tv.x) * tanh_fast(bflo(hv.x) + rv.x)
                      + bfhi(tv.x) * tanh_fast(bfhi(hv.x) + rv.y)
                      + bflo(tv.y) * tanh_fast(bflo(hv.y) + rv.z)
                      + bfhi(tv.y) * tanh_fast(bfhi(hv.y) + rv.w);
#pragma unroll
            for (int off = 8; off; off >>= 1) sum += __shfl_xor(sum, off);
            if (lj == 0 && ei < deg) att_s[wv][ei] = sum;
        }
        float attv = (lane < deg) ? att_s[wv][lane] : -3.4e38f;  // wave-local LDS
        float m = attv;
#pragma unroll
        for (int off = 32; off; off >>= 1) m = fmaxf(m, __shfl_xor(m, off));
        float exv = (lane < deg) ? __expf(attv - m) : 0.f;
        float s_ = exv;
#pragma unroll
        for (int off = 32; off; off >>= 1) s_ += __shfl_xor(s_, off);
        float inv = 1.f / s_;
        if (lane < deg) acsr[b + lane] = exv * inv; // contiguous write
        // --- aggregate emb[src] (2-way unrolled for latency) ---
        float acc = 0.f;
        int i = 0;
        for (; i + 1 < deg; i += 2) {
            float a0 = __shfl(exv, i), a1 = __shfl(exv, i + 1);
            int s0 = (int)(__shfl(se, i) & 0x0FFFFFFFu);
            int s1 = (int)(__shfl(se, i + 1) & 0x0FFFFFFFu);
            float v0 = emb[(long)s0 * DD + lane];
            float v1 = emb[(long)s1 * DD + lane];
            acc = fmaf(v0, a0, acc);
            acc = fmaf(v1, a1, acc);
        }
        if (i < deg) {
            float a0 = __shfl(exv, i);
            int s0 = (int)(__shfl(se, i) & 0x0FFFFFFFu);
            acc = fmaf(emb[(long)s0 * DD + lane], a0, acc);
        }
        Nh = acc * inv;
    } else if (deg > 64) {
        // slow path (deg>64), correctness-first
        float m = -3.4e38f;
        for (int i = 0; i < deg; ++i) {
            unsigned sei = srcet[b + i];
            int s = (int)(sei & 0x0FFFFFFFu);
            int r = (int)(sei >> 28);
            float pv = __uint_as_float(((unsigned)((const unsigned short*)proj)[((long)r * NN + s) * DDR + lane]) << 16);
            float dv = __uint_as_float(((unsigned)((const unsigned short*)proj)[((long)r * NN + g) * DDR + lane]) << 16);
            float rv = rel[r * DDR + lane];
            float term = pv * tanh_fast(dv + rv);
#pragma unroll
            for (int off = 32; off; off >>= 1) term += __shfl_xor(term, off);
            if (lane == 0) acsr[b + i] = term;      // raw logits
            m = fmaxf(m, term);
        }
        float s_ = 0.f;
        for (int i = lane; i < deg; i += 64) s_ += __expf(acsr[b + i] - m);
#pragma unroll
        for (int off = 32; off; off >>= 1) s_ += __shfl_xor(s_, off);
        float inv = 1.f / s_;
        float acc = 0.f;
        for (int i = 0; i < deg; ++i) {
            float raw = acsr[b + i];
            float a = __expf(raw - m) * inv;
            int s = (int)(srcet[b + i] & 0x0FFFFFFFu);
            acc = fmaf(emb[(long)s * DD + lane], a, acc);
            if (lane == 0) acsr[b + i] = a;
        }
        Nh = acc;
    }
    float x = emb[(long)g * DD + lane];
    sm1[wv][lane] = x + Nh;
    sm2[wv][lane] = x * Nh;
    __syncthreads();
    int j = lane & 31;
    const float* __restrict__ WT = (lane < 32) ? &W1T[0][0] : &W2T[0][0];
    const float* __restrict__ sm = (lane < 32) ? &sm1[wv][0] : &sm2[wv][0];
    float accm = (lane < 32) ? b1[j] : b2[j];
#pragma unroll 8
    for (int dd = 0; dd < 64; ++dd)
        accm = fmaf(sm[dd], WT[dd * 33 + j], accm);
    accm = (accm >= 0.f) ? accm : 0.01f * accm;
    float other = __shfl_down(accm, 32);
    float h = accm + other;
    float ss = h * h;
#pragma unroll
    for (int off = 16; off; off >>= 1) ss += __shfl_xor(ss, off);
    float hn = h / fmaxf(sqrtf(ss), 1e-12f);
    out[(long)g * 112 + lane] = x;
    if (lane < 32) out[(long)g * 112 + 64 + j] = hn;
}

// ---- MEGA1: layer-1 aggregation + layer-1 MLP, 32-lane group per dst ----
__global__ void __launch_bounds__(256)
k_mega1(const float* __restrict__ acsr, const unsigned* __restrict__ srcet,
        const unsigned* __restrict__ cnt, const unsigned* __restrict__ basep,
        const float* __restrict__ W1, const float* __restrict__ b1,
        const float* __restrict__ W2, const float* __restrict__ b2,
        float* __restrict__ out)
{
    __shared__ float W1T[32][17];
    __shared__ float W2T[32][17];
    __shared__ float sm1[8][32];
    __shared__ float sm2[8][32];
    int t = threadIdx.x;
#pragma unroll
    for (int i = 0; i < 2; ++i) {
        int idx = i * 256 + t;          // j=idx>>5, dd=idx&31
        W1T[idx & 31][idx >> 5] = W1[idx];
        W2T[idx & 31][idx >> 5] = W2[idx];
    }
    int grp = t >> 5, l5 = t & 31;
    int g = blockIdx.x * 8 + grp;       // NN % 8 == 0: always valid
    int deg = (int)cnt[g];
    float acc = 0.f;
    if (deg > 0) {
        long b = basep[g];
        unsigned se = 0; float a = 0.f;
        if (l5 < deg) { se = srcet[b + l5]; a = acsr[b + l5]; }
        int dmin = (deg < 32) ? deg : 32;
        int i = 0;
        for (; i + 1 < dmin; i += 2) {
            float a0 = __shfl(a, i, 32), a1 = __shfl(a, i + 1, 32);
            int s0 = (int)(__shfl(se, i, 32) & 0x0FFFFFFFu);
            int s1 = (int)(__shfl(se, i + 1, 32) & 0x0FFFFFFFu);
            float v0 = out[(long)s0 * 112 + 64 + l5];
            float v1 = out[(long)s1 * 112 + 64 + l5];
            acc = fmaf(v0, a0, acc);
            acc = fmaf(v1, a1, acc);
        }
        if (i < dmin) {
            float a0 = __shfl(a, i, 32);
            int s0 = (int)(__shfl(se, i, 32) & 0x0FFFFFFFu);
            acc = fmaf(out[(long)s0 * 112 + 64 + l5], a0, acc);
        }
        for (int k = 32; k < deg; ++k) {
            float ak = acsr[b + k];
            int sk = (int)(srcet[b + k] & 0x0FFFFFFFu);
            acc = fmaf(out[(long)sk * 112 + 64 + l5], ak, acc);
        }
    }
    float x = out[(long)g * 112 + 64 + l5];
    sm1[grp][l5] = x + acc;
    sm2[grp][l5] = x * acc;
    __syncthreads();
    int j = l5 & 15;
    const float* __restrict__ WT = (l5 < 16) ? &W1T[0][0] : &W2T[0][0];
    const float* __restrict__ sm = (l5 < 16) ? &sm1[grp][0] : &sm2[grp][0];
    float accm = (l5 < 16) ? b1[j] : b2[j];
#pragma unroll 8
    for (int dd = 0; dd < 32; ++dd)
        accm = fmaf(sm[dd], WT[dd * 17 + j], accm);
    accm = (accm >= 0.f) ? accm : 0.01f * accm;
    float other = __shfl_down(accm, 16, 32);
    float h = accm + other;
    float ss = h * h;
#pragma unroll
    for (int off = 8; off; off >>= 1) ss += __shfl_xor(ss, off);
    float hn = h / fmaxf(sqrtf(ss), 1e-12f);
    if (l5 < 16) out[(long)g * 112 + 96 + j] = hn;
}

// ================= fallback path (ws too small): round-1 kernels =================
__global__ void k_att(const float* __restrict__ emb, const float* __restrict__ rel,
                      const float* __restrict__ WR, const int* __restrict__ src,
                      const int* __restrict__ dst, const int* __restrict__ et,
                      float* __restrict__ att, unsigned* __restrict__ mkey)
{
    int e = (int)((blockIdx.x * blockDim.x + threadIdx.x) >> 6);
    int lane = threadIdx.x & 63;
    if (e >= NE) return;
    int s = src[e], d = dst[e], r = et[e];
    const float* __restrict__ es = emb + (long)s * DD;
    const float* __restrict__ eh = emb + (long)d * DD;
    const float* __restrict__ w  = WR + r * (DD * DDR) + lane;
    float at = 0.f, ah = 0.f;
#pragma unroll 8
    for (int dd = 0; dd < DD; ++dd) {
        float ws = w[dd * DDR];
        at = fmaf(es[dd], ws, at);
        ah = fmaf(eh[dd], ws, ah);
    }
    float term = at * tanhf(ah + rel[r * DDR + lane]);
#pragma unroll
    for (int off = 32; off; off >>= 1) term += __shfl_xor(term, off);
    if (lane == 0) {
        att[e] = term;
        atomicMax(mkey + d, enc_f(term));
    }
}

__global__ void k_expsum(const int* __restrict__ dst, float* __restrict__ att,
                         const unsigned* __restrict__ mkey, float* __restrict__ ssum)
{
    int e = blockIdx.x * blockDim.x + threadIdx.x;
    if (e >= NE) return;
    int d = dst[e];
    float ex = expf(att[e] - dec_f(mkey[d]));
    att[e] = ex;
    atomicAdd(ssum + d, ex);
}

__global__ void k_agg0(const float* __restrict__ emb, const int* __restrict__ src,
                       const int* __restrict__ dst, float* __restrict__ att,
                       const float* __restrict__ ssum, float* __restrict__ Nh)
{
    int e = (int)((blockIdx.x * blockDim.x + threadIdx.x) >> 6);
    int lane = threadIdx.x & 63;
    if (e >= NE) return;
    int s = src[e], d = dst[e];
    float a = att[e] / ssum[d];
    if (lane == 0) att[e] = a;
    float v = emb[(long)s * DD + lane] * a;
    atomicAdd(Nh + (long)d * DD + lane, v);
}

__global__ void k_agg1(const float* __restrict__ out, const int* __restrict__ src,
                       const int* __restrict__ dst, const float* __restrict__ att,
                       float* __restrict__ Nh1)
{
    int idx = blockIdx.x * blockDim.x + threadIdx.x;
    int e = idx >> 5;
    int j = idx & 31;
    if (e >= NE) return;
    int s = src[e], d = dst[e];
    float a = att[e];
    float v = out[(long)s * 112 + 64 + j] * a;
    atomicAdd(Nh1 + (long)d * 32 + j, v);
}

#define NPB0 32
__global__ void __launch_bounds__(256)
k_node0t(const float* __restrict__ emb, const float* __restrict__ Nh,
         const float* __restrict__ W1, const float* __restrict__ b1,
         const float* __restrict__ W2, const float* __restrict__ b2,
         float* __restrict__ out)
{
    __shared__ float W1T[64][33];
    __shared__ float W2T[64][33];
    int t = threadIdx.x;
#pragma unroll
    for (int i = 0; i < 8; ++i) {
        int idx = i * 256 + t;
        W1T[idx & 63][idx >> 6] = W1[idx];
        W2T[idx & 63][idx >> 6] = W2[idx];
    }
    __syncthreads();
    int wv = t >> 6, lane = t & 63, j = lane & 31;
    const float* __restrict__ WT = (lane < 32) ? &W1T[0][0] : &W2T[0][0];
    float bj = (lane < 32) ? b1[j] : b2[j];
    int n0 = blockIdx.x * NPB0;
    int n1 = (n0 + NPB0 < NN) ? n0 + NPB0 : NN;
    for (int node = n0 + wv; node < n1; node += 4) {
        const float* __restrict__ x  = emb + (long)node * DD;
        const float* __restrict__ nh = Nh + (long)node * DD;
        float acc = 0.f;
#pragma unroll 8
        for (int dd = 0; dd < DD; ++dd) {
            float xv = x[dd], nv = nh[dd];
            float v = (lane < 32) ? (xv + nv) : (xv * nv);
            acc = fmaf(v, WT[dd * 33 + j], acc);
        }
        acc += bj;
        acc = (acc >= 0.f) ? acc : 0.01f * acc;
        float other = __shfl_down(acc, 32);
        float h = acc + other;
        float ss = h * h;
#pragma unroll
        for (int off = 16; off; off >>= 1) ss += __shfl_xor(ss, off);
        float hn = h / fmaxf(sqrtf(ss), 1e-12f);
        out[(long)node * 112 + lane] = x[lane];
        if (lane < 32) out[(long)node * 112 + 64 + j] = hn;
    }
}

#define NPB1 32
__global__ void __launch_bounds__(256)
k_node1t(const float* __restrict__ outbuf, const float* __restrict__ Nh1,
         const float* __restrict__ W1, const float* __restrict__ b1,
         const float* __restrict__ W2, const float* __restrict__ b2,
         float* __restrict__ out)
{
    __shared__ float W1T[32][17];
    __shared__ float W2T[32][17];
    int t = threadIdx.x;
#pragma unroll
    for (int i = 0; i < 2; ++i) {
        int idx = i * 256 + t;
        W1T[idx & 31][idx >> 5] = W1[idx];
        W2T[idx & 31][idx >> 5] = W2[idx];
    }
    __syncthreads();
    int grp = t >> 5;
    int l5 = t & 31, j = l5 & 15;
    const float* __restrict__ WT = (l5 < 16) ? &W1T[0][0] : &W2T[0][0];
    float bj = (l5 < 16) ? b1[j] : b2[j];
    int n0 = blockIdx.x * NPB1;
    int n1 = (n0 + NPB1 < NN) ? n0 + NPB1 : NN;
    for (int node = n0 + grp; node < n1; node += 8) {
        const float* __restrict__ x  = outbuf + (long)node * 112 + 64;
        const float* __restrict__ nh = Nh1 + (long)node * 32;
        float acc = 0.f;
#pragma unroll 8
        for (int dd = 0; dd < 32; ++dd) {
            float xv = x[dd], nv = nh[dd];
            float v = (l5 < 16) ? (xv + nv) : (xv * nv);
            acc = fmaf(v, WT[dd * 17 + j], acc);
        }
        acc += bj;
        acc = (acc >= 0.f) ? acc : 0.01f * acc;
        float other = __shfl_down(acc, 16, 32);
        float h = acc + other;
        float ss = h * h;
#pragma unroll
        for (int off = 8; off; off >>= 1) ss += __shfl_xor(ss, off);
        float hn = h / fmaxf(sqrtf(ss), 1e-12f);
        if (l5 < 16) out[(long)node * 112 + 96 + j] = hn;
    }
}

extern "C" void kernel_launch(void* const* d_in, const int* in_sizes, int n_in,
                              void* d_out, int out_size, void* d_ws, size_t ws_size,
                              hipStream_t stream) {
    const float* emb  = (const float*)d_in[0];
    const float* rel  = (const float*)d_in[1];
    const float* WR   = (const float*)d_in[2];
    const float* W1_0 = (const float*)d_in[3];
    const float* b1_0 = (const float*)d_in[4];
    const float* W2_0 = (const float*)d_in[5];
    const float* b2_0 = (const float*)d_in[6];
    const float* W1_1 = (const float*)d_in[7];
    const float* b1_1 = (const float*)d_in[8];
    const float* W2_1 = (const float*)d_in[9];
    const float* b2_1 = (const float*)d_in[10];
    const int*   src  = (const int*)d_in[11];
    const int*   dst  = (const int*)d_in[12];
    const int*   et   = (const int*)d_in[13];
    float* out = (float*)d_out;

    // main-path workspace (4B units):
    // [cnt NN][gcur 64][base NN][curs NN][acsr NE][srcet NE][proj bf16 NR*NN*64]
    unsigned* cnt   = (unsigned*)d_ws;
    unsigned* gcur  = cnt + NN;
    unsigned* basep = cnt + NN + 64;
    unsigned* curs  = cnt + 2 * NN + 64;
    float* acsr  = (float*)d_ws + 3 * NN + 64;
    unsigned* srcet = (unsigned*)(acsr + NE);
    unsigned* proj = srcet + NE;

    size_t need = ((size_t)3 * NN + 64 + 2 * (size_t)NE) * 4
                + (size_t)NN * NR * DDR * 2;

    if (ws_size >= need) {
        hipMemsetAsync(d_ws, 0, (size_t)(NN + 64) * sizeof(unsigned), stream);  // cnt + gcur
        k_hist<<<dim3((NE + 255) / 256), dim3(256), 0, stream>>>(dst, cnt);
        k_projm<<<dim3((NN + 127) / 128, NR), dim3(256), 0, stream>>>(
            emb, WR, (unsigned short*)proj);
        k_base<<<dim3((NN + 255) / 256), dim3(256), 0, stream>>>(cnt, gcur, basep, curs);
        k_scatter2<<<dim3((NE + 255) / 256), dim3(256), 0, stream>>>(
            dst, src, et, curs, srcet);
        k_mega0<<<dim3((NN + 3) / 4), dim3(256), 0, stream>>>(
            emb, proj, rel, cnt, basep, srcet, acsr,
            W1_0, b1_0, W2_0, b2_0, out);
        k_mega1<<<dim3((NN + 7) / 8), dim3(256), 0, stream>>>(
            acsr, srcet, cnt, basep, W1_1, b1_1, W2_1, b2_1, out);
    } else {
        // fallback: round-1 atomic pipeline, old layout
        unsigned* mkey = (unsigned*)d_ws;
        float* ssum = (float*)d_ws + NN;
        float* fNh0 = (float*)d_ws + 2 * NN;
        float* fNh1 = (float*)d_ws + (2 + DD) * NN;
        float* fatt = (float*)d_ws + (2 + DD + 32) * NN;
        hipMemsetAsync(d_ws, 0, (size_t)(2 + DD + 32) * NN * sizeof(float), stream);
        k_att<<<dim3((int)(((long)NE * 64 + 255) / 256)), dim3(256), 0, stream>>>(
            emb, rel, WR, src, dst, et, fatt, mkey);
        k_expsum<<<dim3((NE + 255) / 256), dim3(256), 0, stream>>>(dst, fatt, mkey, ssum);
        k_agg0<<<dim3((int)(((long)NE * 64 + 255) / 256)), dim3(256), 0, stream>>>(
            emb, src, dst, fatt, ssum, fNh0);
        k_node0t<<<dim3((NN + NPB0 - 1) / NPB0), dim3(256), 0, stream>>>(
            emb, fNh0, W1_0, b1_0, W2_0, b2_0, out);
        k_agg1<<<dim3((int)(((long)NE * 32 + 255) / 256)), dim3(256), 0, stream>>>(
            out, src, dst, fatt, fNh1);
        k_node1t<<<dim3((NN + NPB1 - 1) / NPB1), dim3(256), 0, stream>>>(
            out, fNh1, W1_1, b1_1, W2_1, b2_1, out);
    }
}